// Round 11
// baseline (1324.083 us; speedup 1.0000x reference)
//
#include <hip/hip_runtime.h>

#define N_USERS 100000
#define N_ITEMS 50000
#define N_NODES (N_USERS + N_ITEMS)   // 150000
#define DIM 64
#define NNZ_TOTAL 10000000
#define TOTAL (N_NODES * DIM)         // 9,600,000 floats
#define TOTAL4 (TOTAL / 4)            // 2,400,000 float4
#define USZ4 (N_USERS * DIM / 4)      // 1,600,000 float4

#define BROWS 256                     // rows per bucket
#define NB ((N_NODES + BROWS - 1) / BROWS)   // 586
#define SCHUNK 8192                   // edges per scatter chunk
#define SGRD ((NNZ_TOTAL + SCHUNK - 1) / SCHUNK)  // 1221
#define COLMASK 0x3FFFFu              // 18 bits for col

#define CTSH 14                       // column-tile shift: 16384 cols = 2MB bf16
#define NT 10                         // ceil(150000 / 16384)
#define NKEY (BROWS * NT)             // 2560 keys per bucket

#define ROWS_PB 74                    // rows per spmm block (LDS acc 18.9KB)
#define RPW 19                        // rows per wave (4 waves)
#define SPMM_GRID ((N_NODES + ROWS_PB - 1) / ROWS_PB)  // 2028 <= 2048 co-resident

__device__ __forceinline__ float bf2f(unsigned short u) {
    return __uint_as_float(((unsigned)u) << 16);
}
__device__ __forceinline__ unsigned short f2bf(float f) {
    unsigned b = __float_as_uint(f);
    b += 0x7FFFu + ((b >> 16) & 1u);   // RNE
    return (unsigned short)(b >> 16);
}

// ===========================================================================
// init: T0 = bf16(concat(user,item)); acc(d_out) = f32 concat
// ===========================================================================
__global__ __launch_bounds__(256) void k_init(const float4* __restrict__ user,
                                              const float4* __restrict__ item,
                                              ushort4* __restrict__ T0,
                                              float4* __restrict__ acc) {
    const int stride = gridDim.x * blockDim.x;
    for (int i = blockIdx.x * blockDim.x + threadIdx.x; i < TOTAL4; i += stride) {
        float4 v = (i < USZ4) ? user[i] : item[i - USZ4];
        acc[i] = v;
        ushort4 t;
        t.x = f2bf(v.x); t.y = f2bf(v.y); t.z = f2bf(v.z); t.w = f2bf(v.w);
        T0[i] = t;
    }
}

// ===========================================================================
// Bucketed CSR build. cnt matrix layout: cnt[b * SGRD + g]  (b-major)
// ===========================================================================
__global__ __launch_bounds__(256) void k_lhist(const int* __restrict__ row,
                                               int* __restrict__ cnt) {
    __shared__ int h[NB];
    for (int i = threadIdx.x; i < NB; i += 256) h[i] = 0;
    __syncthreads();
    const int g = blockIdx.x;
    const int lo = g * SCHUNK;
    const int hi = (lo + SCHUNK < NNZ_TOTAL) ? lo + SCHUNK : NNZ_TOTAL;
    for (int e = lo + threadIdx.x; e < hi; e += 256)
        atomicAdd(&h[row[e] >> 8], 1);
    __syncthreads();
    for (int b = threadIdx.x; b < NB; b += 256)
        cnt[b * SGRD + g] = h[b];
}

__global__ __launch_bounds__(256) void k_rowsum(const int* __restrict__ cnt,
                                                int* __restrict__ rowsum) {
    __shared__ int lds[256];
    const int b = blockIdx.x;
    const int t = threadIdx.x;
    int s = 0;
    for (int k = t; k < SGRD; k += 256) s += cnt[b * SGRD + k];
    lds[t] = s;
    __syncthreads();
    #pragma unroll
    for (int off = 128; off > 0; off >>= 1) {
        if (t < off) lds[t] += lds[t + off];
        __syncthreads();
    }
    if (t == 0) rowsum[b] = lds[0];
}

__global__ __launch_bounds__(1024) void k_sscan(const int* __restrict__ rowsum,
                                                int* __restrict__ bbase) {
    __shared__ int lds[1024];
    const int t = threadIdx.x;
    const int x = (t < NB) ? rowsum[t] : 0;
    lds[t] = x;
    __syncthreads();
    for (int off = 1; off < 1024; off <<= 1) {
        const int y = (t >= off) ? lds[t - off] : 0;
        __syncthreads();
        lds[t] += y;
        __syncthreads();
    }
    if (t < NB) bbase[t] = lds[t] - x;
    if (t == 1023) bbase[NB] = lds[1023];   // == NNZ
}

__global__ __launch_bounds__(1024) void k_rowscan(int* __restrict__ cnt,
                                                  const int* __restrict__ bbase) {
    __shared__ int lds[1024];
    const int b = blockIdx.x;
    const int t = threadIdx.x;
    const int i0 = 2 * t, i1 = 2 * t + 1;
    const int a0 = (i0 < SGRD) ? cnt[b * SGRD + i0] : 0;
    const int a1 = (i1 < SGRD) ? cnt[b * SGRD + i1] : 0;
    const int s = a0 + a1;
    lds[t] = s;
    __syncthreads();
    for (int off = 1; off < 1024; off <<= 1) {
        const int y = (t >= off) ? lds[t - off] : 0;
        __syncthreads();
        lds[t] += y;
        __syncthreads();
    }
    const int pre = bbase[b] + lds[t] - s;
    if (i0 < SGRD) cnt[b * SGRD + i0] = pre;
    if (i1 < SGRD) cnt[b * SGRD + i1] = pre + a0;
}

// LDS-staged scatter, records staged in LDS (edges read ONCE, sequentially).
__global__ __launch_bounds__(1024) void k_lscatter(const int* __restrict__ row,
                                                   const int* __restrict__ col,
                                                   const float* __restrict__ val,
                                                   const int* __restrict__ cnt,
                                                   const int* __restrict__ bbase,
                                                   uint2* __restrict__ tmp) {
    __shared__ uint2 stage[SCHUNK];   // 64 KB: full records grouped by bucket
    __shared__ int lstartp[1024];     // local bucket starts, padded w/ sentinel
    __shared__ int gbase[NB];
    __shared__ int cur[NB];
    __shared__ int scratch[1024];

    const int g = blockIdx.x;
    const int t = threadIdx.x;
    const int lo = g * SCHUNK;
    const int hi = (lo + SCHUNK < NNZ_TOTAL) ? lo + SCHUNK : NNZ_TOTAL;
    const int n = hi - lo;

    int lcnt = 0;
    if (t < NB) {
        const int base = cnt[t * SGRD + g];
        gbase[t] = base;
        const int nxt = (g == SGRD - 1) ? bbase[t + 1] : cnt[t * SGRD + g + 1];
        lcnt = nxt - base;
    }
    scratch[t] = lcnt;
    __syncthreads();

    for (int off = 1; off < 1024; off <<= 1) {
        const int y = (t >= off) ? scratch[t - off] : 0;
        __syncthreads();
        scratch[t] += y;
        __syncthreads();
    }
    const int ls = (t < NB) ? scratch[t] - lcnt : n;   // sentinel = n
    lstartp[t] = ls;
    if (t < NB) cur[t] = ls;
    __syncthreads();

    for (int e = lo + t; e < hi; e += 1024) {
        const int r = row[e];
        const unsigned meta = ((unsigned)(r & (BROWS - 1)) << 18) | (unsigned)col[e];
        const int p = atomicAdd(&cur[r >> 8], 1);
        stage[p] = make_uint2(meta, __float_as_uint(val[e]));
    }
    __syncthreads();

    for (int l = t; l < n; l += 1024) {
        int blo = 0, bhi = 1024;
        #pragma unroll
        for (int s = 0; s < 10; ++s) {
            const int mid = (blo + bhi) >> 1;
            if (lstartp[mid] <= l) blo = mid; else bhi = mid;
        }
        tmp[gbase[blo] + (l - lstartp[blo])] = stage[l];
    }
}

// per-bucket counting sort by key = (col_tile, local_row): CSR becomes
// TILE-MAJOR within each bucket -> spmm can process tiles as the outer loop
// with contiguous edge segments per (tile, row).
__global__ __launch_bounds__(256) void k_bsort(const uint2* __restrict__ tmp,
                                               uint2* __restrict__ csr,
                                               const int* __restrict__ bbase) {
    __shared__ int cnt[NKEY];
    __shared__ int curl[NKEY];
    __shared__ int part[256];
    const int tid = threadIdx.x;
    const int b = blockIdx.x;
    const int s = bbase[b];
    const int e = bbase[b + 1];

    for (int k = tid; k < NKEY; k += 256) cnt[k] = 0;
    __syncthreads();
    for (int j = s + tid; j < e; j += 256) {
        const unsigned m = tmp[j].x;
        const int key = (int)((m & COLMASK) >> CTSH) * BROWS + (int)(m >> 18);
        atomicAdd(&cnt[key], 1);
    }
    __syncthreads();
    const int lo = tid * NT;
    int ssum = 0;
    #pragma unroll
    for (int k = 0; k < NT; ++k) ssum += cnt[lo + k];
    part[tid] = ssum;
    __syncthreads();
    for (int off = 1; off < 256; off <<= 1) {
        const int y = (tid >= off) ? part[tid - off] : 0;
        __syncthreads();
        part[tid] += y;
        __syncthreads();
    }
    int base = part[tid] - ssum;
    #pragma unroll
    for (int k = 0; k < NT; ++k) {
        const int c = cnt[lo + k];
        curl[lo + k] = base;
        base += c;
    }
    __syncthreads();
    for (int j = s + tid; j < e; j += 256) {
        const uint2 u = tmp[j];
        const unsigned m = u.x;
        const int key = (int)((m & COLMASK) >> CTSH) * BROWS + (int)(m >> 18);
        const int p = atomicAdd(&curl[key], 1);
        csr[s + p] = u;
    }
}

// per-(bucket, tile, local_row) absolute segment offsets: rt_abs[b*NKEY + key]
// (recount from sorted csr; runs after bsort so it can live in dead tmp space)
__global__ __launch_bounds__(256) void k_rtoffs(const uint2* __restrict__ csr,
                                                const int* __restrict__ bbase,
                                                int* __restrict__ rt_abs) {
    __shared__ int cnt[NKEY];
    __shared__ int part[256];
    const int tid = threadIdx.x;
    const int b = blockIdx.x;
    const int s = bbase[b];
    const int e = bbase[b + 1];
    for (int k = tid; k < NKEY; k += 256) cnt[k] = 0;
    __syncthreads();
    for (int j = s + tid; j < e; j += 256) {
        const unsigned m = csr[j].x;
        const int key = (int)((m & COLMASK) >> CTSH) * BROWS + (int)(m >> 18);
        atomicAdd(&cnt[key], 1);
    }
    __syncthreads();
    const int lo = tid * NT;
    int ssum = 0;
    #pragma unroll
    for (int k = 0; k < NT; ++k) ssum += cnt[lo + k];
    part[tid] = ssum;
    __syncthreads();
    for (int off = 1; off < 256; off <<= 1) {
        const int y = (tid >= off) ? part[tid - off] : 0;
        __syncthreads();
        part[tid] += y;
        __syncthreads();
    }
    int base = part[tid] - ssum;
    #pragma unroll
    for (int k = 0; k < NT; ++k) {
        rt_abs[(size_t)b * NKEY + lo + k] = s + base;
        base += cnt[lo + k];
    }
    if (b == 0 && tid == 0) rt_abs[(size_t)NB * NKEY] = NNZ_TOTAL;
}

// ===========================================================================
// Tile-phased SpMM: 2028 co-resident blocks (8/CU), 74 rows/block with
// accumulators in LDS. Outer loop over column tiles -> the whole device
// gathers from one ~2MB table tile at a time (XCD-L2-resident).
// ===========================================================================
template <bool FINAL>
__global__ __launch_bounds__(256, 8) void k_spmm_tile(const ushort4* __restrict__ T4,
                                                      ushort4* __restrict__ U4,
                                                      float4* __restrict__ ACC4,
                                                      const int* __restrict__ rt_abs,
                                                      const uint2* __restrict__ csr) {
    __shared__ float4 accL[ROWS_PB * 16];   // 18,944 B
    const int tid  = threadIdx.x;
    const int lane = tid & 63;
    const int sub  = lane >> 4;
    const int d4   = lane & 15;
    const int w    = tid >> 6;
    const int rbase = blockIdx.x * ROWS_PB;

    for (int i = tid; i < ROWS_PB * 16; i += 256)
        accL[i] = make_float4(0.f, 0.f, 0.f, 0.f);
    __syncthreads();

    const int r0 = w * RPW;
    const int r1 = (r0 + RPW < ROWS_PB) ? r0 + RPW : ROWS_PB;

    for (int t = 0; t < NT; ++t) {
        for (int r = r0; r < r1; ++r) {
            const int gr = rbase + r;
            if (gr >= N_NODES) break;
            const int B  = gr >> 8;
            const int lr = gr & (BROWS - 1);
            const size_t ix = (size_t)B * NKEY + t * BROWS + lr;
            const int s = rt_abs[ix];
            const int e = rt_abs[ix + 1];
            float4 a = make_float4(0.f, 0.f, 0.f, 0.f);
            for (int j = s + sub; j < e; j += 4) {
                const uint2 u = csr[j];
                const ushort4 g = T4[(size_t)(u.x & COLMASK) * 16 + d4];
                const float v = __uint_as_float(u.y);
                a.x += v * bf2f(g.x);
                a.y += v * bf2f(g.y);
                a.z += v * bf2f(g.z);
                a.w += v * bf2f(g.w);
            }
            #pragma unroll
            for (int m = 16; m <= 32; m <<= 1) {
                a.x += __shfl_xor(a.x, m, 64);
                a.y += __shfl_xor(a.y, m, 64);
                a.z += __shfl_xor(a.z, m, 64);
                a.w += __shfl_xor(a.w, m, 64);
            }
            if (sub == 0) {
                float4 c = accL[r * 16 + d4];
                c.x += a.x; c.y += a.y; c.z += a.z; c.w += a.w;
                accL[r * 16 + d4] = c;
            }
        }
        __syncthreads();   // keep block's waves tile-aligned
    }

    // epilogue: write bf16 next-layer table + f32 acc update (coalesced)
    for (int i = tid; i < ROWS_PB * 16; i += 256) {
        const int gr = rbase + (i >> 4);
        if (gr >= N_NODES) break;
        const size_t gi = (size_t)gr * 16 + (i & 15);
        float4 a = ACC4[gi];
        const float4 c = accL[i];
        if (FINAL) {
            a.x = (a.x + c.x) * 0.25f;
            a.y = (a.y + c.y) * 0.25f;
            a.z = (a.z + c.z) * 0.25f;
            a.w = (a.w + c.w) * 0.25f;
            ACC4[gi] = a;
        } else {
            ushort4 tt;
            tt.x = f2bf(c.x); tt.y = f2bf(c.y); tt.z = f2bf(c.z); tt.w = f2bf(c.w);
            U4[gi] = tt;
            a.x += c.x; a.y += c.y; a.z += c.z; a.w += c.w;
            ACC4[gi] = a;
        }
    }
}

// ===========================================================================
// Last-resort fallback (round-1 atomic path; needs only 76.8 MB ws)
// ===========================================================================
__global__ __launch_bounds__(256) void k_init_f32(const float4* __restrict__ user,
                                                  const float4* __restrict__ item,
                                                  float4* __restrict__ A,
                                                  float4* __restrict__ acc) {
    const int stride = gridDim.x * blockDim.x;
    for (int i = blockIdx.x * blockDim.x + threadIdx.x; i < TOTAL4; i += stride) {
        float4 v = (i < USZ4) ? user[i] : item[i - USZ4];
        A[i] = v;
        acc[i] = v;
    }
}

__global__ __launch_bounds__(256) void k_spmm_atomic(const float* __restrict__ A,
                                                     float* __restrict__ B,
                                                     const float* __restrict__ val,
                                                     const int* __restrict__ row,
                                                     const int* __restrict__ col) {
    const int lane = threadIdx.x & 63;
    int wave = blockIdx.x * (blockDim.x >> 6) + (threadIdx.x >> 6);
    const int nw = gridDim.x * (blockDim.x >> 6);
    for (int e = wave; e < NNZ_TOTAL; e += nw) {
        const float x = A[col[e] * DIM + lane];
        unsafeAtomicAdd(&B[row[e] * DIM + lane], val[e] * x);
    }
}

__global__ __launch_bounds__(256) void k_accadd(float4* __restrict__ acc,
                                                const float4* __restrict__ B) {
    const int stride = gridDim.x * blockDim.x;
    for (int i = blockIdx.x * blockDim.x + threadIdx.x; i < TOTAL4; i += stride) {
        float4 a = acc[i];
        const float4 b = B[i];
        a.x += b.x; a.y += b.y; a.z += b.z; a.w += b.w;
        acc[i] = a;
    }
}

__global__ __launch_bounds__(256) void k_final(float4* __restrict__ acc,
                                               const float4* __restrict__ B) {
    const int stride = gridDim.x * blockDim.x;
    for (int i = blockIdx.x * blockDim.x + threadIdx.x; i < TOTAL4; i += stride) {
        float4 a = acc[i];
        const float4 b = B[i];
        a.x = (a.x + b.x) * 0.25f;
        a.y = (a.y + b.y) * 0.25f;
        a.z = (a.z + b.z) * 0.25f;
        a.w = (a.w + b.w) * 0.25f;
        acc[i] = a;
    }
}

extern "C" void kernel_launch(void* const* d_in, const int* in_sizes, int n_in,
                              void* d_out, int out_size, void* d_ws, size_t ws_size,
                              hipStream_t stream) {
    const float* user = (const float*)d_in[0];
    const float* item = (const float*)d_in[1];
    const float* val  = (const float*)d_in[2];
    const int*   row  = (const int*)d_in[3];
    const int*   col  = (const int*)d_in[4];

    float* acc = (float*)d_out;
    const int eltBlocks = 2048;

    // ws layout: region A [0..80MB): cnt matrix during build -> csr
    //            region B [80..160MB): tmp -> T0 (19.2) | T1 (19.2) | rt_abs (6)
    //            misc: bbase, rowsum
    const size_t CSR_BYTES = (size_t)NNZ_TOTAL * 8;            // 80,000,000
    uint2* csr  = (uint2*)d_ws;
    int*   cnt  = (int*)d_ws;
    char*  reg1 = (char*)d_ws + CSR_BYTES;
    uint2* tmp  = (uint2*)reg1;
    ushort4* T0 = (ushort4*)reg1;                               // 19.2MB
    ushort4* T1 = T0 + TOTAL4;                                  // 19.2MB
    int* rt_abs = (int*)(T1 + TOTAL4);                          // NB*NKEY+1 ints ~6MB (dead tmp space)
    int* bbase  = (int*)(reg1 + CSR_BYTES);                     // NB+1
    int* rowsum = bbase + NB + 1;                               // NB

    const size_t needed = 2 * CSR_BYTES + (size_t)(2 * NB + 1) * 4;

    if (ws_size >= needed) {
        // ---- build bucketed, tile-major CSR (no global atomics) ----
        k_lhist<<<SGRD, 256, 0, stream>>>(row, cnt);
        k_rowsum<<<NB, 256, 0, stream>>>(cnt, rowsum);
        k_sscan<<<1, 1024, 0, stream>>>(rowsum, bbase);
        k_rowscan<<<NB, 1024, 0, stream>>>(cnt, bbase);
        k_lscatter<<<SGRD, 1024, 0, stream>>>(row, col, val, cnt, bbase, tmp);
        k_bsort<<<NB, 256, 0, stream>>>(tmp, csr, bbase);
        k_rtoffs<<<NB, 256, 0, stream>>>(csr, bbase, rt_abs);

        // ---- embeddings (T0/T1 overlay tmp; tmp dead after bsort) ----
        k_init<<<eltBlocks, 256, 0, stream>>>((const float4*)user, (const float4*)item,
                                              T0, (float4*)acc);

        // ---- 3 tile-phased SpMM layers ----
        k_spmm_tile<false><<<SPMM_GRID, 256, 0, stream>>>(
            T0, T1, (float4*)acc, rt_abs, csr);
        k_spmm_tile<false><<<SPMM_GRID, 256, 0, stream>>>(
            T1, T0, (float4*)acc, rt_abs, csr);
        k_spmm_tile<true><<<SPMM_GRID, 256, 0, stream>>>(
            T0, T1, (float4*)acc, rt_abs, csr);
        return;
    }

    // ---- last resort: atomic path ----
    float* A2 = (float*)d_ws;
    float* B2 = A2 + TOTAL;
    k_init_f32<<<eltBlocks, 256, 0, stream>>>((const float4*)user, (const float4*)item,
                                              (float4*)A2, (float4*)acc);
    float* Af = A2;
    float* Bf = B2;
    for (int layer = 0; layer < 3; ++layer) {
        hipMemsetAsync(Bf, 0, (size_t)TOTAL * sizeof(float), stream);
        k_spmm_atomic<<<2048, 256, 0, stream>>>(Af, Bf, val, row, col);
        if (layer < 2) {
            k_accadd<<<eltBlocks, 256, 0, stream>>>((float4*)acc, (const float4*)Bf);
            float* t = Af; Af = Bf; Bf = t;
        } else {
            k_final<<<eltBlocks, 256, 0, stream>>>((float4*)acc, (const float4*)Bf);
        }
    }
}

// Round 13
// 1036.491 us; speedup vs baseline: 1.2775x; 1.2775x over previous
//
#include <hip/hip_runtime.h>

#define N_USERS 100000
#define N_ITEMS 50000
#define N_NODES (N_USERS + N_ITEMS)   // 150000
#define DIM 64
#define NNZ_TOTAL 10000000
#define TOTAL (N_NODES * DIM)         // 9,600,000 floats
#define TOTAL4 (TOTAL / 4)            // 2,400,000 float4
#define USZ4 (N_USERS * DIM / 4)      // 1,600,000 float4

#define BROWS 256                     // rows per bucket
#define NB ((N_NODES + BROWS - 1) / BROWS)   // 586
#define SCHUNK 8192                   // edges per scatter chunk
#define SGRD ((NNZ_TOTAL + SCHUNK - 1) / SCHUNK)  // 1221
#define COLMASK 0x3FFFFu              // 18 bits for col

#define CTSH 14                       // column-tile shift: 16384 cols = 2MB bf16
#define NT 10                         // ceil(150000 / 16384)
#define NKEY (BROWS * NT)             // 2560 keys per bucket

#define GROUPS_PB 16                  // 16-lane groups per block
#define ROWS_PG 5                     // rows per group (register accumulators)
#define SPMM_BLOCKS (N_NODES / (GROUPS_PB * ROWS_PG))   // 1875, all co-resident

__device__ __forceinline__ float bf2f(unsigned short u) {
    return __uint_as_float(((unsigned)u) << 16);
}
__device__ __forceinline__ unsigned short f2bf(float f) {
    unsigned b = __float_as_uint(f);
    b += 0x7FFFu + ((b >> 16) & 1u);   // RNE
    return (unsigned short)(b >> 16);
}

// ===========================================================================
// init: T0 = bf16(concat(user,item)); acc(d_out) = f32 concat
// ===========================================================================
__global__ __launch_bounds__(256) void k_init(const float4* __restrict__ user,
                                              const float4* __restrict__ item,
                                              ushort4* __restrict__ T0,
                                              float4* __restrict__ acc) {
    const int stride = gridDim.x * blockDim.x;
    for (int i = blockIdx.x * blockDim.x + threadIdx.x; i < TOTAL4; i += stride) {
        float4 v = (i < USZ4) ? user[i] : item[i - USZ4];
        acc[i] = v;
        ushort4 t;
        t.x = f2bf(v.x); t.y = f2bf(v.y); t.z = f2bf(v.z); t.w = f2bf(v.w);
        T0[i] = t;
    }
}

// ===========================================================================
// Bucketed CSR build. cnt matrix layout: cnt[b * SGRD + g]  (b-major)
// ===========================================================================
__global__ __launch_bounds__(256) void k_lhist(const int* __restrict__ row,
                                               int* __restrict__ cnt) {
    __shared__ int h[NB];
    for (int i = threadIdx.x; i < NB; i += 256) h[i] = 0;
    __syncthreads();
    const int g = blockIdx.x;
    const int lo = g * SCHUNK;
    const int hi = (lo + SCHUNK < NNZ_TOTAL) ? lo + SCHUNK : NNZ_TOTAL;
    for (int e = lo + threadIdx.x; e < hi; e += 256)
        atomicAdd(&h[row[e] >> 8], 1);
    __syncthreads();
    for (int b = threadIdx.x; b < NB; b += 256)
        cnt[b * SGRD + g] = h[b];
}

__global__ __launch_bounds__(256) void k_rowsum(const int* __restrict__ cnt,
                                                int* __restrict__ rowsum) {
    __shared__ int lds[256];
    const int b = blockIdx.x;
    const int t = threadIdx.x;
    int s = 0;
    for (int k = t; k < SGRD; k += 256) s += cnt[b * SGRD + k];
    lds[t] = s;
    __syncthreads();
    #pragma unroll
    for (int off = 128; off > 0; off >>= 1) {
        if (t < off) lds[t] += lds[t + off];
        __syncthreads();
    }
    if (t == 0) rowsum[b] = lds[0];
}

__global__ __launch_bounds__(1024) void k_sscan(const int* __restrict__ rowsum,
                                                int* __restrict__ bbase) {
    __shared__ int lds[1024];
    const int t = threadIdx.x;
    const int x = (t < NB) ? rowsum[t] : 0;
    lds[t] = x;
    __syncthreads();
    for (int off = 1; off < 1024; off <<= 1) {
        const int y = (t >= off) ? lds[t - off] : 0;
        __syncthreads();
        lds[t] += y;
        __syncthreads();
    }
    if (t < NB) bbase[t] = lds[t] - x;
    if (t == 1023) bbase[NB] = lds[1023];   // == NNZ
}

__global__ __launch_bounds__(1024) void k_rowscan(int* __restrict__ cnt,
                                                  const int* __restrict__ bbase) {
    __shared__ int lds[1024];
    const int b = blockIdx.x;
    const int t = threadIdx.x;
    const int i0 = 2 * t, i1 = 2 * t + 1;
    const int a0 = (i0 < SGRD) ? cnt[b * SGRD + i0] : 0;
    const int a1 = (i1 < SGRD) ? cnt[b * SGRD + i1] : 0;
    const int s = a0 + a1;
    lds[t] = s;
    __syncthreads();
    for (int off = 1; off < 1024; off <<= 1) {
        const int y = (t >= off) ? lds[t - off] : 0;
        __syncthreads();
        lds[t] += y;
        __syncthreads();
    }
    const int pre = bbase[b] + lds[t] - s;
    if (i0 < SGRD) cnt[b * SGRD + i0] = pre;
    if (i1 < SGRD) cnt[b * SGRD + i1] = pre + a0;
}

// LDS-staged scatter, records staged in LDS (edges read ONCE, sequentially).
__global__ __launch_bounds__(1024) void k_lscatter(const int* __restrict__ row,
                                                   const int* __restrict__ col,
                                                   const float* __restrict__ val,
                                                   const int* __restrict__ cnt,
                                                   const int* __restrict__ bbase,
                                                   uint2* __restrict__ tmp) {
    __shared__ uint2 stage[SCHUNK];   // 64 KB: full records grouped by bucket
    __shared__ int lstartp[1024];     // local bucket starts, padded w/ sentinel
    __shared__ int gbase[NB];
    __shared__ int cur[NB];
    __shared__ int scratch[1024];

    const int g = blockIdx.x;
    const int t = threadIdx.x;
    const int lo = g * SCHUNK;
    const int hi = (lo + SCHUNK < NNZ_TOTAL) ? lo + SCHUNK : NNZ_TOTAL;
    const int n = hi - lo;

    int lcnt = 0;
    if (t < NB) {
        const int base = cnt[t * SGRD + g];
        gbase[t] = base;
        const int nxt = (g == SGRD - 1) ? bbase[t + 1] : cnt[t * SGRD + g + 1];
        lcnt = nxt - base;
    }
    scratch[t] = lcnt;
    __syncthreads();

    for (int off = 1; off < 1024; off <<= 1) {
        const int y = (t >= off) ? scratch[t - off] : 0;
        __syncthreads();
        scratch[t] += y;
        __syncthreads();
    }
    const int ls = (t < NB) ? scratch[t] - lcnt : n;   // sentinel = n
    lstartp[t] = ls;
    if (t < NB) cur[t] = ls;
    __syncthreads();

    for (int e = lo + t; e < hi; e += 1024) {
        const int r = row[e];
        const unsigned meta = ((unsigned)(r & (BROWS - 1)) << 18) | (unsigned)col[e];
        const int p = atomicAdd(&cur[r >> 8], 1);
        stage[p] = make_uint2(meta, __float_as_uint(val[e]));
    }
    __syncthreads();

    for (int l = t; l < n; l += 1024) {
        int blo = 0, bhi = 1024;
        #pragma unroll
        for (int s = 0; s < 10; ++s) {
            const int mid = (blo + bhi) >> 1;
            if (lstartp[mid] <= l) blo = mid; else bhi = mid;
        }
        tmp[gbase[blo] + (l - lstartp[blo])] = stage[l];
    }
}

// per-bucket counting sort by key = (col_tile, local_row): CSR becomes
// TILE-MAJOR within each bucket. (rt_abs emitted by the SEPARATE k_rtoffs
// pass below -- fusing it here races with other blocks' tmp reads.)
__global__ __launch_bounds__(256) void k_bsort(const uint2* __restrict__ tmp,
                                               uint2* __restrict__ csr,
                                               const int* __restrict__ bbase) {
    __shared__ int cnt[NKEY];
    __shared__ int curl[NKEY];
    __shared__ int part[256];
    const int tid = threadIdx.x;
    const int b = blockIdx.x;
    const int s = bbase[b];
    const int e = bbase[b + 1];

    for (int k = tid; k < NKEY; k += 256) cnt[k] = 0;
    __syncthreads();
    for (int j = s + tid; j < e; j += 256) {
        const unsigned m = tmp[j].x;
        const int key = (int)((m & COLMASK) >> CTSH) * BROWS + (int)(m >> 18);
        atomicAdd(&cnt[key], 1);
    }
    __syncthreads();
    const int lo = tid * NT;
    int ssum = 0;
    #pragma unroll
    for (int k = 0; k < NT; ++k) ssum += cnt[lo + k];
    part[tid] = ssum;
    __syncthreads();
    for (int off = 1; off < 256; off <<= 1) {
        const int y = (tid >= off) ? part[tid - off] : 0;
        __syncthreads();
        part[tid] += y;
        __syncthreads();
    }
    int base = part[tid] - ssum;
    #pragma unroll
    for (int k = 0; k < NT; ++k) {
        const int c = cnt[lo + k];
        curl[lo + k] = base;
        base += c;
    }
    __syncthreads();
    for (int j = s + tid; j < e; j += 256) {
        const uint2 u = tmp[j];
        const unsigned m = u.x;
        const int key = (int)((m & COLMASK) >> CTSH) * BROWS + (int)(m >> 18);
        const int p = atomicAdd(&curl[key], 1);
        csr[s + p] = u;
    }
}

// per-(bucket, tile, local_row) absolute segment offsets: rt_abs[b*NKEY+key].
// Runs AFTER bsort, reads csr (region A) only -> safe to write rt_abs into
// the dead tmp region.
__global__ __launch_bounds__(256) void k_rtoffs(const uint2* __restrict__ csr,
                                                const int* __restrict__ bbase,
                                                int* __restrict__ rt_abs) {
    __shared__ int cnt[NKEY];
    __shared__ int part[256];
    const int tid = threadIdx.x;
    const int b = blockIdx.x;
    const int s = bbase[b];
    const int e = bbase[b + 1];
    for (int k = tid; k < NKEY; k += 256) cnt[k] = 0;
    __syncthreads();
    for (int j = s + tid; j < e; j += 256) {
        const unsigned m = csr[j].x;
        const int key = (int)((m & COLMASK) >> CTSH) * BROWS + (int)(m >> 18);
        atomicAdd(&cnt[key], 1);
    }
    __syncthreads();
    const int lo = tid * NT;
    int ssum = 0;
    #pragma unroll
    for (int k = 0; k < NT; ++k) ssum += cnt[lo + k];
    part[tid] = ssum;
    __syncthreads();
    for (int off = 1; off < 256; off <<= 1) {
        const int y = (tid >= off) ? part[tid - off] : 0;
        __syncthreads();
        part[tid] += y;
        __syncthreads();
    }
    int base = part[tid] - ssum;
    #pragma unroll
    for (int k = 0; k < NT; ++k) {
        rt_abs[(size_t)b * NKEY + lo + k] = s + base;
        base += cnt[lo + k];
    }
    if (b == 0 && tid == 0) rt_abs[(size_t)NB * NKEY] = NNZ_TOTAL;
}

// ===========================================================================
// Tile-phased SpMM, register accumulators: 1875 co-resident blocks (8/CU),
// 16 groups/block x 5 rows/group. Tiles outer (lockstep via __syncthreads);
// each 16-lane group walks its rows' per-tile segments serially, acc in VGPRs,
// no shuffles, no LDS. Gather = 16 lanes x 8B = one 128B line (L2-resident).
// ===========================================================================
template <bool FINAL>
__global__ __launch_bounds__(256, 8) void k_spmm_reg(const ushort4* __restrict__ T4,
                                                     ushort4* __restrict__ U4,
                                                     float4* __restrict__ ACC4,
                                                     const int* __restrict__ rt_abs,
                                                     const uint2* __restrict__ csr) {
    const int tid = threadIdx.x;
    const int d4  = tid & 15;
    const int gid = tid >> 4;
    const int gg  = blockIdx.x * GROUPS_PB + gid;
    const int row0 = gg * ROWS_PG;

    float4 acc[ROWS_PG];
    #pragma unroll
    for (int ri = 0; ri < ROWS_PG; ++ri)
        acc[ri] = make_float4(0.f, 0.f, 0.f, 0.f);

    for (int t = 0; t < NT; ++t) {
        #pragma unroll
        for (int ri = 0; ri < ROWS_PG; ++ri) {
            const int gr = row0 + ri;
            const int B  = gr >> 8;
            const int lr = gr & (BROWS - 1);
            const size_t ix = (size_t)B * NKEY + t * BROWS + lr;
            int j = rt_abs[ix];
            const int e = rt_abs[ix + 1];
            float4 a = acc[ri];
            for (; j + 1 < e; j += 2) {
                const uint2 u0 = csr[j];
                const uint2 u1 = csr[j + 1];
                const ushort4 g0 = T4[(size_t)(u0.x & COLMASK) * 16 + d4];
                const ushort4 g1 = T4[(size_t)(u1.x & COLMASK) * 16 + d4];
                const float v0 = __uint_as_float(u0.y);
                const float v1 = __uint_as_float(u1.y);
                a.x += v0 * bf2f(g0.x) + v1 * bf2f(g1.x);
                a.y += v0 * bf2f(g0.y) + v1 * bf2f(g1.y);
                a.z += v0 * bf2f(g0.z) + v1 * bf2f(g1.z);
                a.w += v0 * bf2f(g0.w) + v1 * bf2f(g1.w);
            }
            if (j < e) {
                const uint2 u0 = csr[j];
                const ushort4 g0 = T4[(size_t)(u0.x & COLMASK) * 16 + d4];
                const float v0 = __uint_as_float(u0.y);
                a.x += v0 * bf2f(g0.x);
                a.y += v0 * bf2f(g0.y);
                a.z += v0 * bf2f(g0.z);
                a.w += v0 * bf2f(g0.w);
            }
            acc[ri] = a;
        }
        __syncthreads();   // tile lockstep within the block
    }

    // epilogue: one write per row (16 lanes x 16B = 256B contiguous per row)
    #pragma unroll
    for (int ri = 0; ri < ROWS_PG; ++ri) {
        const int gr = row0 + ri;
        const size_t gi = (size_t)gr * 16 + d4;
        float4 a = ACC4[gi];
        const float4 c = acc[ri];
        if (FINAL) {
            a.x = (a.x + c.x) * 0.25f;
            a.y = (a.y + c.y) * 0.25f;
            a.z = (a.z + c.z) * 0.25f;
            a.w = (a.w + c.w) * 0.25f;
            ACC4[gi] = a;
        } else {
            ushort4 tt;
            tt.x = f2bf(c.x); tt.y = f2bf(c.y); tt.z = f2bf(c.z); tt.w = f2bf(c.w);
            U4[gi] = tt;
            a.x += c.x; a.y += c.y; a.z += c.z; a.w += c.w;
            ACC4[gi] = a;
        }
    }
}

// ===========================================================================
// Last-resort fallback (round-1 atomic path; needs only 76.8 MB ws)
// ===========================================================================
__global__ __launch_bounds__(256) void k_init_f32(const float4* __restrict__ user,
                                                  const float4* __restrict__ item,
                                                  float4* __restrict__ A,
                                                  float4* __restrict__ acc) {
    const int stride = gridDim.x * blockDim.x;
    for (int i = blockIdx.x * blockDim.x + threadIdx.x; i < TOTAL4; i += stride) {
        float4 v = (i < USZ4) ? user[i] : item[i - USZ4];
        A[i] = v;
        acc[i] = v;
    }
}

__global__ __launch_bounds__(256) void k_spmm_atomic(const float* __restrict__ A,
                                                     float* __restrict__ B,
                                                     const float* __restrict__ val,
                                                     const int* __restrict__ row,
                                                     const int* __restrict__ col) {
    const int lane = threadIdx.x & 63;
    int wave = blockIdx.x * (blockDim.x >> 6) + (threadIdx.x >> 6);
    const int nw = gridDim.x * (blockDim.x >> 6);
    for (int e = wave; e < NNZ_TOTAL; e += nw) {
        const float x = A[col[e] * DIM + lane];
        unsafeAtomicAdd(&B[row[e] * DIM + lane], val[e] * x);
    }
}

__global__ __launch_bounds__(256) void k_accadd(float4* __restrict__ acc,
                                                const float4* __restrict__ B) {
    const int stride = gridDim.x * blockDim.x;
    for (int i = blockIdx.x * blockDim.x + threadIdx.x; i < TOTAL4; i += stride) {
        float4 a = acc[i];
        const float4 b = B[i];
        a.x += b.x; a.y += b.y; a.z += b.z; a.w += b.w;
        acc[i] = a;
    }
}

__global__ __launch_bounds__(256) void k_final(float4* __restrict__ acc,
                                               const float4* __restrict__ B) {
    const int stride = gridDim.x * blockDim.x;
    for (int i = blockIdx.x * blockDim.x + threadIdx.x; i < TOTAL4; i += stride) {
        float4 a = acc[i];
        const float4 b = B[i];
        a.x = (a.x + b.x) * 0.25f;
        a.y = (a.y + b.y) * 0.25f;
        a.z = (a.z + b.z) * 0.25f;
        a.w = (a.w + b.w) * 0.25f;
        acc[i] = a;
    }
}

extern "C" void kernel_launch(void* const* d_in, const int* in_sizes, int n_in,
                              void* d_out, int out_size, void* d_ws, size_t ws_size,
                              hipStream_t stream) {
    const float* user = (const float*)d_in[0];
    const float* item = (const float*)d_in[1];
    const float* val  = (const float*)d_in[2];
    const int*   row  = (const int*)d_in[3];
    const int*   col  = (const int*)d_in[4];

    float* acc = (float*)d_out;
    const int eltBlocks = 2048;

    // ws layout: region A [0..80MB): cnt matrix during build -> csr
    //            region B [80..160MB): tmp -> T0 (19.2) | T1 (19.2) | rt_abs (6)
    //            misc: bbase, rowsum
    const size_t CSR_BYTES = (size_t)NNZ_TOTAL * 8;            // 80,000,000
    uint2* csr  = (uint2*)d_ws;
    int*   cnt  = (int*)d_ws;
    char*  reg1 = (char*)d_ws + CSR_BYTES;
    uint2* tmp  = (uint2*)reg1;
    ushort4* T0 = (ushort4*)reg1;                               // 19.2MB
    ushort4* T1 = T0 + TOTAL4;                                  // 19.2MB
    int* rt_abs = (int*)(T1 + TOTAL4);                          // NB*NKEY+1 ints ~6MB (dead tmp space)
    int* bbase  = (int*)(reg1 + CSR_BYTES);                     // NB+1
    int* rowsum = bbase + NB + 1;                               // NB

    const size_t needed = 2 * CSR_BYTES + (size_t)(2 * NB + 1) * 4;

    if (ws_size >= needed) {
        // ---- build bucketed, tile-major CSR (no global atomics) ----
        k_lhist<<<SGRD, 256, 0, stream>>>(row, cnt);
        k_rowsum<<<NB, 256, 0, stream>>>(cnt, rowsum);
        k_sscan<<<1, 1024, 0, stream>>>(rowsum, bbase);
        k_rowscan<<<NB, 1024, 0, stream>>>(cnt, bbase);
        k_lscatter<<<SGRD, 1024, 0, stream>>>(row, col, val, cnt, bbase, tmp);
        k_bsort<<<NB, 256, 0, stream>>>(tmp, csr, bbase);
        k_rtoffs<<<NB, 256, 0, stream>>>(csr, bbase, rt_abs);   // after bsort: tmp is dead

        // ---- embeddings (T0/T1 overlay tmp; tmp dead after bsort) ----
        k_init<<<eltBlocks, 256, 0, stream>>>((const float4*)user, (const float4*)item,
                                              T0, (float4*)acc);

        // ---- 3 tile-phased SpMM layers (register accumulators) ----
        k_spmm_reg<false><<<SPMM_BLOCKS, 256, 0, stream>>>(
            T0, T1, (float4*)acc, rt_abs, csr);
        k_spmm_reg<false><<<SPMM_BLOCKS, 256, 0, stream>>>(
            T1, T0, (float4*)acc, rt_abs, csr);
        k_spmm_reg<true><<<SPMM_BLOCKS, 256, 0, stream>>>(
            T0, T1, (float4*)acc, rt_abs, csr);
        return;
    }

    // ---- last resort: atomic path ----
    float* A2 = (float*)d_ws;
    float* B2 = A2 + TOTAL;
    k_init_f32<<<eltBlocks, 256, 0, stream>>>((const float4*)user, (const float4*)item,
                                              (float4*)A2, (float4*)acc);
    float* Af = A2;
    float* Bf = B2;
    for (int layer = 0; layer < 3; ++layer) {
        hipMemsetAsync(Bf, 0, (size_t)TOTAL * sizeof(float), stream);
        k_spmm_atomic<<<2048, 256, 0, stream>>>(Af, Bf, val, row, col);
        if (layer < 2) {
            k_accadd<<<eltBlocks, 256, 0, stream>>>((float4*)acc, (const float4*)Bf);
            float* t = Af; Af = Bf; Bf = t;
        } else {
            k_final<<<eltBlocks, 256, 0, stream>>>((float4*)acc, (const float4*)Bf);
        }
    }
}

// Round 14
// 1015.749 us; speedup vs baseline: 1.3036x; 1.0204x over previous
//
#include <hip/hip_runtime.h>

#define N_USERS 100000
#define N_ITEMS 50000
#define N_NODES (N_USERS + N_ITEMS)   // 150000
#define DIM 64
#define NNZ_TOTAL 10000000
#define TOTAL (N_NODES * DIM)         // 9,600,000 floats
#define TOTAL4 (TOTAL / 4)            // 2,400,000 float4
#define USZ4 (N_USERS * DIM / 4)      // 1,600,000 float4

#define BROWS 256                     // rows per bucket
#define NB ((N_NODES + BROWS - 1) / BROWS)   // 586
#define SCHUNK 8192                   // edges per scatter chunk
#define SGRD ((NNZ_TOTAL + SCHUNK - 1) / SCHUNK)  // 1221
#define COLMASK 0x3FFFFu              // 18 bits for col

#define CTSH 15                       // column-tile shift: 32768 cols = 4MB bf16
#define NT 5                          // ceil(150000 / 32768)
#define NKEY (BROWS * NT)             // 1280 keys per bucket

#define GROUPS_PB 16                  // 16-lane groups per block
#define ROWS_PG 5                     // rows per group (register accumulators)
#define SPMM_BLOCKS (N_NODES / (GROUPS_PB * ROWS_PG))   // 1875, all co-resident

__device__ __forceinline__ float bf2f(unsigned short u) {
    return __uint_as_float(((unsigned)u) << 16);
}
__device__ __forceinline__ unsigned short f2bf(float f) {
    unsigned b = __float_as_uint(f);
    b += 0x7FFFu + ((b >> 16) & 1u);   // RNE
    return (unsigned short)(b >> 16);
}

// ===========================================================================
// init: T0 = bf16(concat(user,item)); acc(d_out) = f32 concat
// ===========================================================================
__global__ __launch_bounds__(256) void k_init(const float4* __restrict__ user,
                                              const float4* __restrict__ item,
                                              ushort4* __restrict__ T0,
                                              float4* __restrict__ acc) {
    const int stride = gridDim.x * blockDim.x;
    for (int i = blockIdx.x * blockDim.x + threadIdx.x; i < TOTAL4; i += stride) {
        float4 v = (i < USZ4) ? user[i] : item[i - USZ4];
        acc[i] = v;
        ushort4 t;
        t.x = f2bf(v.x); t.y = f2bf(v.y); t.z = f2bf(v.z); t.w = f2bf(v.w);
        T0[i] = t;
    }
}

// ===========================================================================
// Bucketed CSR build. cnt matrix layout: cnt[b * SGRD + g]  (b-major)
// ===========================================================================
__global__ __launch_bounds__(256) void k_lhist(const int* __restrict__ row,
                                               int* __restrict__ cnt) {
    __shared__ int h[NB];
    for (int i = threadIdx.x; i < NB; i += 256) h[i] = 0;
    __syncthreads();
    const int g = blockIdx.x;
    const int lo = g * SCHUNK;
    const int hi = (lo + SCHUNK < NNZ_TOTAL) ? lo + SCHUNK : NNZ_TOTAL;
    for (int e = lo + threadIdx.x; e < hi; e += 256)
        atomicAdd(&h[row[e] >> 8], 1);
    __syncthreads();
    for (int b = threadIdx.x; b < NB; b += 256)
        cnt[b * SGRD + g] = h[b];
}

__global__ __launch_bounds__(256) void k_rowsum(const int* __restrict__ cnt,
                                                int* __restrict__ rowsum) {
    __shared__ int lds[256];
    const int b = blockIdx.x;
    const int t = threadIdx.x;
    int s = 0;
    for (int k = t; k < SGRD; k += 256) s += cnt[b * SGRD + k];
    lds[t] = s;
    __syncthreads();
    #pragma unroll
    for (int off = 128; off > 0; off >>= 1) {
        if (t < off) lds[t] += lds[t + off];
        __syncthreads();
    }
    if (t == 0) rowsum[b] = lds[0];
}

__global__ __launch_bounds__(1024) void k_sscan(const int* __restrict__ rowsum,
                                                int* __restrict__ bbase) {
    __shared__ int lds[1024];
    const int t = threadIdx.x;
    const int x = (t < NB) ? rowsum[t] : 0;
    lds[t] = x;
    __syncthreads();
    for (int off = 1; off < 1024; off <<= 1) {
        const int y = (t >= off) ? lds[t - off] : 0;
        __syncthreads();
        lds[t] += y;
        __syncthreads();
    }
    if (t < NB) bbase[t] = lds[t] - x;
    if (t == 1023) bbase[NB] = lds[1023];   // == NNZ
}

__global__ __launch_bounds__(1024) void k_rowscan(int* __restrict__ cnt,
                                                  const int* __restrict__ bbase) {
    __shared__ int lds[1024];
    const int b = blockIdx.x;
    const int t = threadIdx.x;
    const int i0 = 2 * t, i1 = 2 * t + 1;
    const int a0 = (i0 < SGRD) ? cnt[b * SGRD + i0] : 0;
    const int a1 = (i1 < SGRD) ? cnt[b * SGRD + i1] : 0;
    const int s = a0 + a1;
    lds[t] = s;
    __syncthreads();
    for (int off = 1; off < 1024; off <<= 1) {
        const int y = (t >= off) ? lds[t - off] : 0;
        __syncthreads();
        lds[t] += y;
        __syncthreads();
    }
    const int pre = bbase[b] + lds[t] - s;
    if (i0 < SGRD) cnt[b * SGRD + i0] = pre;
    if (i1 < SGRD) cnt[b * SGRD + i1] = pre + a0;
}

// LDS-staged scatter, records staged in LDS (edges read ONCE, sequentially).
__global__ __launch_bounds__(1024) void k_lscatter(const int* __restrict__ row,
                                                   const int* __restrict__ col,
                                                   const float* __restrict__ val,
                                                   const int* __restrict__ cnt,
                                                   const int* __restrict__ bbase,
                                                   uint2* __restrict__ tmp) {
    __shared__ uint2 stage[SCHUNK];   // 64 KB: full records grouped by bucket
    __shared__ int lstartp[1024];     // local bucket starts, padded w/ sentinel
    __shared__ int gbase[NB];
    __shared__ int cur[NB];
    __shared__ int scratch[1024];

    const int g = blockIdx.x;
    const int t = threadIdx.x;
    const int lo = g * SCHUNK;
    const int hi = (lo + SCHUNK < NNZ_TOTAL) ? lo + SCHUNK : NNZ_TOTAL;
    const int n = hi - lo;

    int lcnt = 0;
    if (t < NB) {
        const int base = cnt[t * SGRD + g];
        gbase[t] = base;
        const int nxt = (g == SGRD - 1) ? bbase[t + 1] : cnt[t * SGRD + g + 1];
        lcnt = nxt - base;
    }
    scratch[t] = lcnt;
    __syncthreads();

    for (int off = 1; off < 1024; off <<= 1) {
        const int y = (t >= off) ? scratch[t - off] : 0;
        __syncthreads();
        scratch[t] += y;
        __syncthreads();
    }
    const int ls = (t < NB) ? scratch[t] - lcnt : n;   // sentinel = n
    lstartp[t] = ls;
    if (t < NB) cur[t] = ls;
    __syncthreads();

    for (int e = lo + t; e < hi; e += 1024) {
        const int r = row[e];
        const unsigned meta = ((unsigned)(r & (BROWS - 1)) << 18) | (unsigned)col[e];
        const int p = atomicAdd(&cur[r >> 8], 1);
        stage[p] = make_uint2(meta, __float_as_uint(val[e]));
    }
    __syncthreads();

    for (int l = t; l < n; l += 1024) {
        int blo = 0, bhi = 1024;
        #pragma unroll
        for (int s = 0; s < 10; ++s) {
            const int mid = (blo + bhi) >> 1;
            if (lstartp[mid] <= l) blo = mid; else bhi = mid;
        }
        tmp[gbase[blo] + (l - lstartp[blo])] = stage[l];
    }
}

// per-bucket counting sort by key = (col_tile, local_row): CSR becomes
// TILE-MAJOR within each bucket. (rt_abs emitted by the SEPARATE k_rtoffs
// pass below -- fusing it here races with other blocks' tmp reads.)
__global__ __launch_bounds__(256) void k_bsort(const uint2* __restrict__ tmp,
                                               uint2* __restrict__ csr,
                                               const int* __restrict__ bbase) {
    __shared__ int cnt[NKEY];
    __shared__ int curl[NKEY];
    __shared__ int part[256];
    const int tid = threadIdx.x;
    const int b = blockIdx.x;
    const int s = bbase[b];
    const int e = bbase[b + 1];

    for (int k = tid; k < NKEY; k += 256) cnt[k] = 0;
    __syncthreads();
    for (int j = s + tid; j < e; j += 256) {
        const unsigned m = tmp[j].x;
        const int key = (int)((m & COLMASK) >> CTSH) * BROWS + (int)(m >> 18);
        atomicAdd(&cnt[key], 1);
    }
    __syncthreads();
    const int lo = tid * NT;
    int ssum = 0;
    #pragma unroll
    for (int k = 0; k < NT; ++k) ssum += cnt[lo + k];
    part[tid] = ssum;
    __syncthreads();
    for (int off = 1; off < 256; off <<= 1) {
        const int y = (tid >= off) ? part[tid - off] : 0;
        __syncthreads();
        part[tid] += y;
        __syncthreads();
    }
    int base = part[tid] - ssum;
    #pragma unroll
    for (int k = 0; k < NT; ++k) {
        const int c = cnt[lo + k];
        curl[lo + k] = base;
        base += c;
    }
    __syncthreads();
    for (int j = s + tid; j < e; j += 256) {
        const uint2 u = tmp[j];
        const unsigned m = u.x;
        const int key = (int)((m & COLMASK) >> CTSH) * BROWS + (int)(m >> 18);
        const int p = atomicAdd(&curl[key], 1);
        csr[s + p] = u;
    }
}

// per-(bucket, tile, local_row) absolute segment offsets: rt_abs[b*NKEY+key].
// Runs AFTER bsort, reads csr (region A) only -> safe to write rt_abs into
// the dead tmp region.
__global__ __launch_bounds__(256) void k_rtoffs(const uint2* __restrict__ csr,
                                                const int* __restrict__ bbase,
                                                int* __restrict__ rt_abs) {
    __shared__ int cnt[NKEY];
    __shared__ int part[256];
    const int tid = threadIdx.x;
    const int b = blockIdx.x;
    const int s = bbase[b];
    const int e = bbase[b + 1];
    for (int k = tid; k < NKEY; k += 256) cnt[k] = 0;
    __syncthreads();
    for (int j = s + tid; j < e; j += 256) {
        const unsigned m = csr[j].x;
        const int key = (int)((m & COLMASK) >> CTSH) * BROWS + (int)(m >> 18);
        atomicAdd(&cnt[key], 1);
    }
    __syncthreads();
    const int lo = tid * NT;
    int ssum = 0;
    #pragma unroll
    for (int k = 0; k < NT; ++k) ssum += cnt[lo + k];
    part[tid] = ssum;
    __syncthreads();
    for (int off = 1; off < 256; off <<= 1) {
        const int y = (tid >= off) ? part[tid - off] : 0;
        __syncthreads();
        part[tid] += y;
        __syncthreads();
    }
    int base = part[tid] - ssum;
    #pragma unroll
    for (int k = 0; k < NT; ++k) {
        rt_abs[(size_t)b * NKEY + lo + k] = s + base;
        base += cnt[lo + k];
    }
    if (b == 0 && tid == 0) rt_abs[(size_t)NB * NKEY] = NNZ_TOTAL;
}

// ===========================================================================
// Tile-phased SpMM v2: 1875 co-resident blocks (8/CU), 16 groups x 5 rows,
// acc in VGPRs. Per tile: batch-prefetch all 10 segment bounds, then walk
// each segment with an unroll-4 pipeline (4 gathers in flight / group).
// 32-bit gather indices (SGPR base + voffset).
// ===========================================================================
template <bool FINAL>
__global__ __launch_bounds__(256, 8) void k_spmm_reg(const ushort4* __restrict__ T4,
                                                     ushort4* __restrict__ U4,
                                                     float4* __restrict__ ACC4,
                                                     const int* __restrict__ rt_abs,
                                                     const uint2* __restrict__ csr) {
    const int tid = threadIdx.x;
    const unsigned d4 = tid & 15;
    const int gid = tid >> 4;
    const int gg  = blockIdx.x * GROUPS_PB + gid;
    const int row0 = gg * ROWS_PG;
    const unsigned long long* __restrict__ csr8 = (const unsigned long long*)csr;

    float4 acc[ROWS_PG];
    #pragma unroll
    for (int ri = 0; ri < ROWS_PG; ++ri)
        acc[ri] = make_float4(0.f, 0.f, 0.f, 0.f);

    for (int t = 0; t < NT; ++t) {
        // batch-prefetch all segment bounds (10 independent loads in flight)
        int js[ROWS_PG], es[ROWS_PG];
        #pragma unroll
        for (int ri = 0; ri < ROWS_PG; ++ri) {
            const int gr = row0 + ri;
            const int B  = gr >> 8;
            const int lr = gr & (BROWS - 1);
            const size_t ix = (size_t)B * NKEY + t * BROWS + lr;
            js[ri] = rt_abs[ix];
            es[ri] = rt_abs[ix + 1];
        }
        #pragma unroll
        for (int ri = 0; ri < ROWS_PG; ++ri) {
            int j = js[ri];
            const int e = es[ri];
            float4 a = acc[ri];
            // unroll-4: 4 records + 4 independent gathers in flight
            for (; j + 3 < e; j += 4) {
                const unsigned long long r0 = csr8[j];
                const unsigned long long r1 = csr8[j + 1];
                const unsigned long long r2 = csr8[j + 2];
                const unsigned long long r3 = csr8[j + 3];
                const ushort4 g0 = T4[((unsigned)r0 & COLMASK) * 16u + d4];
                const ushort4 g1 = T4[((unsigned)r1 & COLMASK) * 16u + d4];
                const ushort4 g2 = T4[((unsigned)r2 & COLMASK) * 16u + d4];
                const ushort4 g3 = T4[((unsigned)r3 & COLMASK) * 16u + d4];
                const float v0 = __uint_as_float((unsigned)(r0 >> 32));
                const float v1 = __uint_as_float((unsigned)(r1 >> 32));
                const float v2 = __uint_as_float((unsigned)(r2 >> 32));
                const float v3 = __uint_as_float((unsigned)(r3 >> 32));
                a.x += v0 * bf2f(g0.x) + v1 * bf2f(g1.x) + v2 * bf2f(g2.x) + v3 * bf2f(g3.x);
                a.y += v0 * bf2f(g0.y) + v1 * bf2f(g1.y) + v2 * bf2f(g2.y) + v3 * bf2f(g3.y);
                a.z += v0 * bf2f(g0.z) + v1 * bf2f(g1.z) + v2 * bf2f(g2.z) + v3 * bf2f(g3.z);
                a.w += v0 * bf2f(g0.w) + v1 * bf2f(g1.w) + v2 * bf2f(g2.w) + v3 * bf2f(g3.w);
            }
            for (; j + 1 < e; j += 2) {
                const unsigned long long r0 = csr8[j];
                const unsigned long long r1 = csr8[j + 1];
                const ushort4 g0 = T4[((unsigned)r0 & COLMASK) * 16u + d4];
                const ushort4 g1 = T4[((unsigned)r1 & COLMASK) * 16u + d4];
                const float v0 = __uint_as_float((unsigned)(r0 >> 32));
                const float v1 = __uint_as_float((unsigned)(r1 >> 32));
                a.x += v0 * bf2f(g0.x) + v1 * bf2f(g1.x);
                a.y += v0 * bf2f(g0.y) + v1 * bf2f(g1.y);
                a.z += v0 * bf2f(g0.z) + v1 * bf2f(g1.z);
                a.w += v0 * bf2f(g0.w) + v1 * bf2f(g1.w);
            }
            if (j < e) {
                const unsigned long long r0 = csr8[j];
                const ushort4 g0 = T4[((unsigned)r0 & COLMASK) * 16u + d4];
                const float v0 = __uint_as_float((unsigned)(r0 >> 32));
                a.x += v0 * bf2f(g0.x);
                a.y += v0 * bf2f(g0.y);
                a.z += v0 * bf2f(g0.z);
                a.w += v0 * bf2f(g0.w);
            }
            acc[ri] = a;
        }
        __syncthreads();   // tile lockstep within the block
    }

    // epilogue: one write per row (16 lanes x 16B = 256B contiguous per row)
    #pragma unroll
    for (int ri = 0; ri < ROWS_PG; ++ri) {
        const int gr = row0 + ri;
        const size_t gi = (size_t)gr * 16 + d4;
        float4 a = ACC4[gi];
        const float4 c = acc[ri];
        if (FINAL) {
            a.x = (a.x + c.x) * 0.25f;
            a.y = (a.y + c.y) * 0.25f;
            a.z = (a.z + c.z) * 0.25f;
            a.w = (a.w + c.w) * 0.25f;
            ACC4[gi] = a;
        } else {
            ushort4 tt;
            tt.x = f2bf(c.x); tt.y = f2bf(c.y); tt.z = f2bf(c.z); tt.w = f2bf(c.w);
            U4[gi] = tt;
            a.x += c.x; a.y += c.y; a.z += c.z; a.w += c.w;
            ACC4[gi] = a;
        }
    }
}

// ===========================================================================
// Last-resort fallback (round-1 atomic path; needs only 76.8 MB ws)
// ===========================================================================
__global__ __launch_bounds__(256) void k_init_f32(const float4* __restrict__ user,
                                                  const float4* __restrict__ item,
                                                  float4* __restrict__ A,
                                                  float4* __restrict__ acc) {
    const int stride = gridDim.x * blockDim.x;
    for (int i = blockIdx.x * blockDim.x + threadIdx.x; i < TOTAL4; i += stride) {
        float4 v = (i < USZ4) ? user[i] : item[i - USZ4];
        A[i] = v;
        acc[i] = v;
    }
}

__global__ __launch_bounds__(256) void k_spmm_atomic(const float* __restrict__ A,
                                                     float* __restrict__ B,
                                                     const float* __restrict__ val,
                                                     const int* __restrict__ row,
                                                     const int* __restrict__ col) {
    const int lane = threadIdx.x & 63;
    int wave = blockIdx.x * (blockDim.x >> 6) + (threadIdx.x >> 6);
    const int nw = gridDim.x * (blockDim.x >> 6);
    for (int e = wave; e < NNZ_TOTAL; e += nw) {
        const float x = A[col[e] * DIM + lane];
        unsafeAtomicAdd(&B[row[e] * DIM + lane], val[e] * x);
    }
}

__global__ __launch_bounds__(256) void k_accadd(float4* __restrict__ acc,
                                                const float4* __restrict__ B) {
    const int stride = gridDim.x * blockDim.x;
    for (int i = blockIdx.x * blockDim.x + threadIdx.x; i < TOTAL4; i += stride) {
        float4 a = acc[i];
        const float4 b = B[i];
        a.x += b.x; a.y += b.y; a.z += b.z; a.w += b.w;
        acc[i] = a;
    }
}

__global__ __launch_bounds__(256) void k_final(float4* __restrict__ acc,
                                               const float4* __restrict__ B) {
    const int stride = gridDim.x * blockDim.x;
    for (int i = blockIdx.x * blockDim.x + threadIdx.x; i < TOTAL4; i += stride) {
        float4 a = acc[i];
        const float4 b = B[i];
        a.x = (a.x + b.x) * 0.25f;
        a.y = (a.y + b.y) * 0.25f;
        a.z = (a.z + b.z) * 0.25f;
        a.w = (a.w + b.w) * 0.25f;
        acc[i] = a;
    }
}

extern "C" void kernel_launch(void* const* d_in, const int* in_sizes, int n_in,
                              void* d_out, int out_size, void* d_ws, size_t ws_size,
                              hipStream_t stream) {
    const float* user = (const float*)d_in[0];
    const float* item = (const float*)d_in[1];
    const float* val  = (const float*)d_in[2];
    const int*   row  = (const int*)d_in[3];
    const int*   col  = (const int*)d_in[4];

    float* acc = (float*)d_out;
    const int eltBlocks = 2048;

    // ws layout: region A [0..80MB): cnt matrix during build -> csr
    //            region B [80..160MB): tmp -> T0 (19.2) | T1 (19.2) | rt_abs (3)
    //            misc: bbase, rowsum
    const size_t CSR_BYTES = (size_t)NNZ_TOTAL * 8;            // 80,000,000
    uint2* csr  = (uint2*)d_ws;
    int*   cnt  = (int*)d_ws;
    char*  reg1 = (char*)d_ws + CSR_BYTES;
    uint2* tmp  = (uint2*)reg1;
    ushort4* T0 = (ushort4*)reg1;                               // 19.2MB
    ushort4* T1 = T0 + TOTAL4;                                  // 19.2MB
    int* rt_abs = (int*)(T1 + TOTAL4);                          // NB*NKEY+1 ints ~3MB (dead tmp space)
    int* bbase  = (int*)(reg1 + CSR_BYTES);                     // NB+1
    int* rowsum = bbase + NB + 1;                               // NB

    const size_t needed = 2 * CSR_BYTES + (size_t)(2 * NB + 1) * 4;

    if (ws_size >= needed) {
        // ---- build bucketed, tile-major CSR (no global atomics) ----
        k_lhist<<<SGRD, 256, 0, stream>>>(row, cnt);
        k_rowsum<<<NB, 256, 0, stream>>>(cnt, rowsum);
        k_sscan<<<1, 1024, 0, stream>>>(rowsum, bbase);
        k_rowscan<<<NB, 1024, 0, stream>>>(cnt, bbase);
        k_lscatter<<<SGRD, 1024, 0, stream>>>(row, col, val, cnt, bbase, tmp);
        k_bsort<<<NB, 256, 0, stream>>>(tmp, csr, bbase);
        k_rtoffs<<<NB, 256, 0, stream>>>(csr, bbase, rt_abs);   // after bsort: tmp is dead

        // ---- embeddings (T0/T1 overlay tmp; tmp dead after bsort) ----
        k_init<<<eltBlocks, 256, 0, stream>>>((const float4*)user, (const float4*)item,
                                              T0, (float4*)acc);

        // ---- 3 tile-phased SpMM layers (register accumulators) ----
        k_spmm_reg<false><<<SPMM_BLOCKS, 256, 0, stream>>>(
            T0, T1, (float4*)acc, rt_abs, csr);
        k_spmm_reg<false><<<SPMM_BLOCKS, 256, 0, stream>>>(
            T1, T0, (float4*)acc, rt_abs, csr);
        k_spmm_reg<true><<<SPMM_BLOCKS, 256, 0, stream>>>(
            T0, T1, (float4*)acc, rt_abs, csr);
        return;
    }

    // ---- last resort: atomic path ----
    float* A2 = (float*)d_ws;
    float* B2 = A2 + TOTAL;
    k_init_f32<<<eltBlocks, 256, 0, stream>>>((const float4*)user, (const float4*)item,
                                              (float4*)A2, (float4*)acc);
    float* Af = A2;
    float* Bf = B2;
    for (int layer = 0; layer < 3; ++layer) {
        hipMemsetAsync(Bf, 0, (size_t)TOTAL * sizeof(float), stream);
        k_spmm_atomic<<<2048, 256, 0, stream>>>(Af, Bf, val, row, col);
        if (layer < 2) {
            k_accadd<<<eltBlocks, 256, 0, stream>>>((float4*)acc, (const float4*)Bf);
            float* t = Af; Af = Bf; Bf = t;
        } else {
            k_final<<<eltBlocks, 256, 0, stream>>>((float4*)acc, (const float4*)Bf);
        }
    }
}

// Round 15
// 691.994 us; speedup vs baseline: 1.9134x; 1.4679x over previous
//
#include <hip/hip_runtime.h>

#define N_USERS 100000
#define N_ITEMS 50000
#define N_NODES (N_USERS + N_ITEMS)   // 150000
#define DIM 64
#define NNZ_TOTAL 10000000
#define TOTAL (N_NODES * DIM)         // 9,600,000 floats
#define TOTAL4 (TOTAL / 4)            // 2,400,000 float4
#define USZ4 (N_USERS * DIM / 4)      // 1,600,000 float4

#define BROWS 256                     // rows per bucket
#define NB ((N_NODES + BROWS - 1) / BROWS)   // 586
#define SCHUNK 8192                   // edges per scatter chunk
#define SGRD ((NNZ_TOTAL + SCHUNK - 1) / SCHUNK)  // 1221
#define COLMASK 0x3FFFFu              // 18 bits for col

#define VENC 1638300.0f               // encode: q = round(val * 16383/0.01)
#define VDEC 6.1038881e-07f           // decode: val = q * 0.01/16383

__device__ __forceinline__ float bf2f(unsigned short u) {
    return __uint_as_float(((unsigned)u) << 16);
}
__device__ __forceinline__ unsigned short f2bf(float f) {
    unsigned b = __float_as_uint(f);
    b += 0x7FFFu + ((b >> 16) & 1u);   // RNE
    return (unsigned short)(b >> 16);
}

// ===========================================================================
// init: T0 = bf16(concat(user,item)); acc(d_out) = f32 concat
// ===========================================================================
__global__ __launch_bounds__(256) void k_init(const float4* __restrict__ user,
                                              const float4* __restrict__ item,
                                              ushort4* __restrict__ T0,
                                              float4* __restrict__ acc) {
    const int stride = gridDim.x * blockDim.x;
    for (int i = blockIdx.x * blockDim.x + threadIdx.x; i < TOTAL4; i += stride) {
        float4 v = (i < USZ4) ? user[i] : item[i - USZ4];
        acc[i] = v;
        ushort4 t;
        t.x = f2bf(v.x); t.y = f2bf(v.y); t.z = f2bf(v.z); t.w = f2bf(v.w);
        T0[i] = t;
    }
}

// ===========================================================================
// Bucketed CSR build. cnt matrix layout: cnt[b * SGRD + g]  (b-major)
// ===========================================================================
__global__ __launch_bounds__(256) void k_lhist(const int* __restrict__ row,
                                               int* __restrict__ cnt) {
    __shared__ int h[NB];
    for (int i = threadIdx.x; i < NB; i += 256) h[i] = 0;
    __syncthreads();
    const int g = blockIdx.x;
    const int lo = g * SCHUNK;
    const int hi = (lo + SCHUNK < NNZ_TOTAL) ? lo + SCHUNK : NNZ_TOTAL;
    for (int e = lo + threadIdx.x; e < hi; e += 256)
        atomicAdd(&h[row[e] >> 8], 1);
    __syncthreads();
    for (int b = threadIdx.x; b < NB; b += 256)
        cnt[b * SGRD + g] = h[b];
}

__global__ __launch_bounds__(256) void k_rowsum(const int* __restrict__ cnt,
                                                int* __restrict__ rowsum) {
    __shared__ int lds[256];
    const int b = blockIdx.x;
    const int t = threadIdx.x;
    int s = 0;
    for (int k = t; k < SGRD; k += 256) s += cnt[b * SGRD + k];
    lds[t] = s;
    __syncthreads();
    #pragma unroll
    for (int off = 128; off > 0; off >>= 1) {
        if (t < off) lds[t] += lds[t + off];
        __syncthreads();
    }
    if (t == 0) rowsum[b] = lds[0];
}

__global__ __launch_bounds__(1024) void k_sscan(const int* __restrict__ rowsum,
                                                int* __restrict__ bbase) {
    __shared__ int lds[1024];
    const int t = threadIdx.x;
    const int x = (t < NB) ? rowsum[t] : 0;
    lds[t] = x;
    __syncthreads();
    for (int off = 1; off < 1024; off <<= 1) {
        const int y = (t >= off) ? lds[t - off] : 0;
        __syncthreads();
        lds[t] += y;
        __syncthreads();
    }
    if (t < NB) bbase[t] = lds[t] - x;
    if (t == 1023) bbase[NB] = lds[1023];   // == NNZ
}

__global__ __launch_bounds__(1024) void k_rowscan(int* __restrict__ cnt,
                                                  const int* __restrict__ bbase) {
    __shared__ int lds[1024];
    const int b = blockIdx.x;
    const int t = threadIdx.x;
    const int i0 = 2 * t, i1 = 2 * t + 1;
    const int a0 = (i0 < SGRD) ? cnt[b * SGRD + i0] : 0;
    const int a1 = (i1 < SGRD) ? cnt[b * SGRD + i1] : 0;
    const int s = a0 + a1;
    lds[t] = s;
    __syncthreads();
    for (int off = 1; off < 1024; off <<= 1) {
        const int y = (t >= off) ? lds[t - off] : 0;
        __syncthreads();
        lds[t] += y;
        __syncthreads();
    }
    const int pre = bbase[b] + lds[t] - s;
    if (i0 < SGRD) cnt[b * SGRD + i0] = pre;
    if (i1 < SGRD) cnt[b * SGRD + i1] = pre + a0;
}

// LDS-staged scatter, records staged in LDS (edges read ONCE, sequentially).
__global__ __launch_bounds__(1024) void k_lscatter(const int* __restrict__ row,
                                                   const int* __restrict__ col,
                                                   const float* __restrict__ val,
                                                   const int* __restrict__ cnt,
                                                   const int* __restrict__ bbase,
                                                   uint2* __restrict__ tmp) {
    __shared__ uint2 stage[SCHUNK];   // 64 KB: full records grouped by bucket
    __shared__ int lstartp[1024];     // local bucket starts, padded w/ sentinel
    __shared__ int gbase[NB];
    __shared__ int cur[NB];
    __shared__ int scratch[1024];

    const int g = blockIdx.x;
    const int t = threadIdx.x;
    const int lo = g * SCHUNK;
    const int hi = (lo + SCHUNK < NNZ_TOTAL) ? lo + SCHUNK : NNZ_TOTAL;
    const int n = hi - lo;

    int lcnt = 0;
    if (t < NB) {
        const int base = cnt[t * SGRD + g];
        gbase[t] = base;
        const int nxt = (g == SGRD - 1) ? bbase[t + 1] : cnt[t * SGRD + g + 1];
        lcnt = nxt - base;
    }
    scratch[t] = lcnt;
    __syncthreads();

    for (int off = 1; off < 1024; off <<= 1) {
        const int y = (t >= off) ? scratch[t - off] : 0;
        __syncthreads();
        scratch[t] += y;
        __syncthreads();
    }
    const int ls = (t < NB) ? scratch[t] - lcnt : n;   // sentinel = n
    lstartp[t] = ls;
    if (t < NB) cur[t] = ls;
    __syncthreads();

    for (int e = lo + t; e < hi; e += 1024) {
        const int r = row[e];
        const unsigned meta = ((unsigned)(r & (BROWS - 1)) << 18) | (unsigned)col[e];
        const int p = atomicAdd(&cur[r >> 8], 1);
        stage[p] = make_uint2(meta, __float_as_uint(val[e]));
    }
    __syncthreads();

    for (int l = t; l < n; l += 1024) {
        int blo = 0, bhi = 1024;
        #pragma unroll
        for (int s = 0; s < 10; ++s) {
            const int mid = (blo + bhi) >> 1;
            if (lstartp[mid] <= l) blo = mid; else bhi = mid;
        }
        tmp[gbase[blo] + (l - lstartp[blo])] = stage[l];
    }
}

// per-bucket counting sort (256 keys = local row), emits PACKED 4-byte CSR
// records (q<<18 | col) and row_offs. Bucket region ~137 KB L2-resident.
__global__ __launch_bounds__(256) void k_bsort(const uint2* __restrict__ tmp,
                                               unsigned* __restrict__ csr,
                                               const int* __restrict__ bbase,
                                               int* __restrict__ row_offs) {
    __shared__ int cnt[BROWS];
    __shared__ int roff[BROWS];
    __shared__ int curl[BROWS];
    const int tid = threadIdx.x;
    const int b = blockIdx.x;
    const int s = bbase[b];
    const int e = bbase[b + 1];

    cnt[tid] = 0;
    __syncthreads();
    for (int j = s + tid; j < e; j += 256)
        atomicAdd(&cnt[tmp[j].x >> 18], 1);
    __syncthreads();
    if (tid == 0) {
        int a = 0;
        #pragma unroll
        for (int k = 0; k < BROWS; ++k) { roff[k] = a; a += cnt[k]; }
    }
    __syncthreads();
    {
        const int gr = b * BROWS + tid;
        if (gr < N_NODES) row_offs[gr] = s + roff[tid];
        curl[tid] = s + roff[tid];
    }
    __syncthreads();
    for (int j = s + tid; j < e; j += 256) {
        const uint2 u = tmp[j];
        const int p = atomicAdd(&curl[u.x >> 18], 1);
        const unsigned q = __float2uint_rn(__uint_as_float(u.y) * VENC);   // 14 bits
        csr[p] = (q << 18) | (u.x & COLMASK);
    }
    if (b == 0 && tid == 0) row_offs[N_NODES] = NNZ_TOTAL;
}

// ===========================================================================
// CSR SpMM, bf16 gather table, 4-byte packed records (round-8 structure):
// one wave per row; lane = sub*16 + d4; unroll-4; f32 acc; fused acc update.
// ===========================================================================
template <bool FINAL>
__global__ __launch_bounds__(256) void k_spmm_bf16(const ushort4* __restrict__ T4,
                                                   ushort4* __restrict__ U4,
                                                   float4* __restrict__ ACC4,
                                                   const int* __restrict__ offs,
                                                   const unsigned* __restrict__ csr) {
    const int lane = threadIdx.x & 63;
    const int sub  = lane >> 4;
    const int d4   = lane & 15;
    const int r = blockIdx.x * 4 + (threadIdx.x >> 6);
    const int s = offs[r];
    const int e = offs[r + 1];
    float4 acc = make_float4(0.f, 0.f, 0.f, 0.f);
    int j = s + sub;
    for (; j + 12 < e; j += 16) {
        const unsigned u0 = csr[j];
        const unsigned u1 = csr[j + 4];
        const unsigned u2 = csr[j + 8];
        const unsigned u3 = csr[j + 12];
        const ushort4 g0 = T4[(size_t)(u0 & COLMASK) * 16 + d4];
        const ushort4 g1 = T4[(size_t)(u1 & COLMASK) * 16 + d4];
        const ushort4 g2 = T4[(size_t)(u2 & COLMASK) * 16 + d4];
        const ushort4 g3 = T4[(size_t)(u3 & COLMASK) * 16 + d4];
        const float v0 = (float)(u0 >> 18) * VDEC;
        const float v1 = (float)(u1 >> 18) * VDEC;
        const float v2 = (float)(u2 >> 18) * VDEC;
        const float v3 = (float)(u3 >> 18) * VDEC;
        acc.x += v0 * bf2f(g0.x) + v1 * bf2f(g1.x) + v2 * bf2f(g2.x) + v3 * bf2f(g3.x);
        acc.y += v0 * bf2f(g0.y) + v1 * bf2f(g1.y) + v2 * bf2f(g2.y) + v3 * bf2f(g3.y);
        acc.z += v0 * bf2f(g0.z) + v1 * bf2f(g1.z) + v2 * bf2f(g2.z) + v3 * bf2f(g3.z);
        acc.w += v0 * bf2f(g0.w) + v1 * bf2f(g1.w) + v2 * bf2f(g2.w) + v3 * bf2f(g3.w);
    }
    for (; j + 4 < e; j += 8) {
        const unsigned u0 = csr[j];
        const unsigned u1 = csr[j + 4];
        const ushort4 g0 = T4[(size_t)(u0 & COLMASK) * 16 + d4];
        const ushort4 g1 = T4[(size_t)(u1 & COLMASK) * 16 + d4];
        const float v0 = (float)(u0 >> 18) * VDEC;
        const float v1 = (float)(u1 >> 18) * VDEC;
        acc.x += v0 * bf2f(g0.x) + v1 * bf2f(g1.x);
        acc.y += v0 * bf2f(g0.y) + v1 * bf2f(g1.y);
        acc.z += v0 * bf2f(g0.z) + v1 * bf2f(g1.z);
        acc.w += v0 * bf2f(g0.w) + v1 * bf2f(g1.w);
    }
    if (j < e) {
        const unsigned u0 = csr[j];
        const ushort4 g0 = T4[(size_t)(u0 & COLMASK) * 16 + d4];
        const float v0 = (float)(u0 >> 18) * VDEC;
        acc.x += v0 * bf2f(g0.x);
        acc.y += v0 * bf2f(g0.y);
        acc.z += v0 * bf2f(g0.z);
        acc.w += v0 * bf2f(g0.w);
    }
    #pragma unroll
    for (int m = 16; m <= 32; m <<= 1) {
        acc.x += __shfl_xor(acc.x, m, 64);
        acc.y += __shfl_xor(acc.y, m, 64);
        acc.z += __shfl_xor(acc.z, m, 64);
        acc.w += __shfl_xor(acc.w, m, 64);
    }
    if (sub == 0) {
        const size_t idx = (size_t)r * 16 + d4;
        float4 a = ACC4[idx];
        if (FINAL) {
            a.x = (a.x + acc.x) * 0.25f;
            a.y = (a.y + acc.y) * 0.25f;
            a.z = (a.z + acc.z) * 0.25f;
            a.w = (a.w + acc.w) * 0.25f;
            ACC4[idx] = a;
        } else {
            ushort4 t;
            t.x = f2bf(acc.x); t.y = f2bf(acc.y); t.z = f2bf(acc.z); t.w = f2bf(acc.w);
            U4[idx] = t;
            a.x += acc.x;
            a.y += acc.y;
            a.z += acc.z;
            a.w += acc.w;
            ACC4[idx] = a;
        }
    }
}

// ===========================================================================
// Last-resort fallback (round-1 atomic path; needs only 76.8 MB ws)
// ===========================================================================
__global__ __launch_bounds__(256) void k_init_f32(const float4* __restrict__ user,
                                                  const float4* __restrict__ item,
                                                  float4* __restrict__ A,
                                                  float4* __restrict__ acc) {
    const int stride = gridDim.x * blockDim.x;
    for (int i = blockIdx.x * blockDim.x + threadIdx.x; i < TOTAL4; i += stride) {
        float4 v = (i < USZ4) ? user[i] : item[i - USZ4];
        A[i] = v;
        acc[i] = v;
    }
}

__global__ __launch_bounds__(256) void k_spmm_atomic(const float* __restrict__ A,
                                                     float* __restrict__ B,
                                                     const float* __restrict__ val,
                                                     const int* __restrict__ row,
                                                     const int* __restrict__ col) {
    const int lane = threadIdx.x & 63;
    int wave = blockIdx.x * (blockDim.x >> 6) + (threadIdx.x >> 6);
    const int nw = gridDim.x * (blockDim.x >> 6);
    for (int e = wave; e < NNZ_TOTAL; e += nw) {
        const float x = A[col[e] * DIM + lane];
        unsafeAtomicAdd(&B[row[e] * DIM + lane], val[e] * x);
    }
}

__global__ __launch_bounds__(256) void k_accadd(float4* __restrict__ acc,
                                                const float4* __restrict__ B) {
    const int stride = gridDim.x * blockDim.x;
    for (int i = blockIdx.x * blockDim.x + threadIdx.x; i < TOTAL4; i += stride) {
        float4 a = acc[i];
        const float4 b = B[i];
        a.x += b.x; a.y += b.y; a.z += b.z; a.w += b.w;
        acc[i] = a;
    }
}

__global__ __launch_bounds__(256) void k_final(float4* __restrict__ acc,
                                               const float4* __restrict__ B) {
    const int stride = gridDim.x * blockDim.x;
    for (int i = blockIdx.x * blockDim.x + threadIdx.x; i < TOTAL4; i += stride) {
        float4 a = acc[i];
        const float4 b = B[i];
        a.x = (a.x + b.x) * 0.25f;
        a.y = (a.y + b.y) * 0.25f;
        a.z = (a.z + b.z) * 0.25f;
        a.w = (a.w + b.w) * 0.25f;
        acc[i] = a;
    }
}

extern "C" void kernel_launch(void* const* d_in, const int* in_sizes, int n_in,
                              void* d_out, int out_size, void* d_ws, size_t ws_size,
                              hipStream_t stream) {
    const float* user = (const float*)d_in[0];
    const float* item = (const float*)d_in[1];
    const float* val  = (const float*)d_in[2];
    const int*   row  = (const int*)d_in[3];
    const int*   col  = (const int*)d_in[4];

    float* acc = (float*)d_out;
    const int eltBlocks = 2048;

    // ws layout: region A [0..40MB): cnt matrix (2.9MB) during build -> csr (packed u32)
    //            region B [40..120MB): tmp (80MB) -> T0 (19.2) | T1 (19.2) after bsort
    //            misc: row_offs, bbase, rowsum
    const size_t CSR_BYTES = (size_t)NNZ_TOTAL * 4;            // 40,000,000
    unsigned* csr = (unsigned*)d_ws;
    int*   cnt  = (int*)d_ws;                                   // 2.9MB, dead before bsort writes csr
    char*  reg1 = (char*)d_ws + CSR_BYTES;
    uint2* tmp  = (uint2*)reg1;                                 // 80MB
    ushort4* T0 = (ushort4*)reg1;                               // 19.2MB (overlays tmp after bsort)
    ushort4* T1 = T0 + TOTAL4;                                  // 19.2MB
    int* row_offs = (int*)(reg1 + (size_t)NNZ_TOTAL * 8);       // N_NODES+1
    int* bbase    = row_offs + N_NODES + 1;                     // NB+1
    int* rowsum   = bbase + NB + 1;                             // NB

    const size_t needed =
        CSR_BYTES + (size_t)NNZ_TOTAL * 8 + (size_t)(N_NODES + 1 + 2 * NB + 2) * 4;

    if (ws_size >= needed) {
        // ---- build bucketed CSR (no global atomics; LDS record staging) ----
        k_lhist<<<SGRD, 256, 0, stream>>>(row, cnt);
        k_rowsum<<<NB, 256, 0, stream>>>(cnt, rowsum);
        k_sscan<<<1, 1024, 0, stream>>>(rowsum, bbase);
        k_rowscan<<<NB, 1024, 0, stream>>>(cnt, bbase);
        k_lscatter<<<SGRD, 1024, 0, stream>>>(row, col, val, cnt, bbase, tmp);
        k_bsort<<<NB, 256, 0, stream>>>(tmp, csr, bbase, row_offs);

        // ---- embeddings (T0/T1 overlay tmp; tmp dead after bsort) ----
        k_init<<<eltBlocks, 256, 0, stream>>>((const float4*)user, (const float4*)item,
                                              T0, (float4*)acc);

        const int rowBlocks = N_NODES / 4;   // 37500
        k_spmm_bf16<false><<<rowBlocks, 256, 0, stream>>>(
            T0, T1, (float4*)acc, row_offs, csr);
        k_spmm_bf16<false><<<rowBlocks, 256, 0, stream>>>(
            T1, T0, (float4*)acc, row_offs, csr);
        k_spmm_bf16<true><<<rowBlocks, 256, 0, stream>>>(
            T0, T1, (float4*)acc, row_offs, csr);
        return;
    }

    // ---- last resort: atomic path ----
    float* A2 = (float*)d_ws;
    float* B2 = A2 + TOTAL;
    k_init_f32<<<eltBlocks, 256, 0, stream>>>((const float4*)user, (const float4*)item,
                                              (float4*)A2, (float4*)acc);
    float* Af = A2;
    float* Bf = B2;
    for (int layer = 0; layer < 3; ++layer) {
        hipMemsetAsync(Bf, 0, (size_t)TOTAL * sizeof(float), stream);
        k_spmm_atomic<<<2048, 256, 0, stream>>>(Af, Bf, val, row, col);
        if (layer < 2) {
            k_accadd<<<eltBlocks, 256, 0, stream>>>((float4*)acc, (const float4*)Bf);
            float* t = Af; Af = Bf; Bf = t;
        } else {
            k_final<<<eltBlocks, 256, 0, stream>>>((float4*)acc, (const float4*)Bf);
        }
    }
}

// Round 16
// 679.524 us; speedup vs baseline: 1.9485x; 1.0184x over previous
//
#include <hip/hip_runtime.h>

#define N_USERS 100000
#define N_ITEMS 50000
#define N_NODES (N_USERS + N_ITEMS)   // 150000
#define DIM 64
#define NNZ_TOTAL 10000000
#define TOTAL (N_NODES * DIM)         // 9,600,000 floats
#define TOTAL4 (TOTAL / 4)            // 2,400,000 float4
#define USZ4 (N_USERS * DIM / 4)      // 1,600,000 float4

#define BROWS 256                     // rows per bucket
#define NB ((N_NODES + BROWS - 1) / BROWS)   // 586
#define SCHUNK 8192                   // edges per scatter chunk
#define SGRD ((NNZ_TOTAL + SCHUNK - 1) / SCHUNK)  // 1221
#define COLMASK 0x3FFFFu              // 18 bits for col

#define VENC 1638300.0f               // encode: q = round(val * 16383/0.01)
#define VDEC 6.1038881e-07f           // decode: val = q * 0.01/16383

__device__ __forceinline__ float bf2f(unsigned short u) {
    return __uint_as_float(((unsigned)u) << 16);
}
__device__ __forceinline__ unsigned short f2bf(float f) {
    unsigned b = __float_as_uint(f);
    b += 0x7FFFu + ((b >> 16) & 1u);   // RNE
    return (unsigned short)(b >> 16);
}

// ===========================================================================
// init: T0 = bf16(concat(user,item))  (acc no longer materialized)
// ===========================================================================
__global__ __launch_bounds__(256) void k_init(const float4* __restrict__ user,
                                              const float4* __restrict__ item,
                                              ushort4* __restrict__ T0) {
    const int stride = gridDim.x * blockDim.x;
    for (int i = blockIdx.x * blockDim.x + threadIdx.x; i < TOTAL4; i += stride) {
        float4 v = (i < USZ4) ? user[i] : item[i - USZ4];
        ushort4 t;
        t.x = f2bf(v.x); t.y = f2bf(v.y); t.z = f2bf(v.z); t.w = f2bf(v.w);
        T0[i] = t;
    }
}

// ===========================================================================
// Bucketed CSR build. cnt matrix layout: cnt[b * SGRD + g]  (b-major)
// ===========================================================================
__global__ __launch_bounds__(256) void k_lhist(const int* __restrict__ row,
                                               int* __restrict__ cnt) {
    __shared__ int h[NB];
    for (int i = threadIdx.x; i < NB; i += 256) h[i] = 0;
    __syncthreads();
    const int g = blockIdx.x;
    const int lo = g * SCHUNK;
    const int hi = (lo + SCHUNK < NNZ_TOTAL) ? lo + SCHUNK : NNZ_TOTAL;
    for (int e = lo + threadIdx.x; e < hi; e += 256)
        atomicAdd(&h[row[e] >> 8], 1);
    __syncthreads();
    for (int b = threadIdx.x; b < NB; b += 256)
        cnt[b * SGRD + g] = h[b];
}

__global__ __launch_bounds__(256) void k_rowsum(const int* __restrict__ cnt,
                                                int* __restrict__ rowsum) {
    __shared__ int lds[256];
    const int b = blockIdx.x;
    const int t = threadIdx.x;
    int s = 0;
    for (int k = t; k < SGRD; k += 256) s += cnt[b * SGRD + k];
    lds[t] = s;
    __syncthreads();
    #pragma unroll
    for (int off = 128; off > 0; off >>= 1) {
        if (t < off) lds[t] += lds[t + off];
        __syncthreads();
    }
    if (t == 0) rowsum[b] = lds[0];
}

__global__ __launch_bounds__(1024) void k_sscan(const int* __restrict__ rowsum,
                                                int* __restrict__ bbase) {
    __shared__ int lds[1024];
    const int t = threadIdx.x;
    const int x = (t < NB) ? rowsum[t] : 0;
    lds[t] = x;
    __syncthreads();
    for (int off = 1; off < 1024; off <<= 1) {
        const int y = (t >= off) ? lds[t - off] : 0;
        __syncthreads();
        lds[t] += y;
        __syncthreads();
    }
    if (t < NB) bbase[t] = lds[t] - x;
    if (t == 1023) bbase[NB] = lds[1023];   // == NNZ
}

__global__ __launch_bounds__(1024) void k_rowscan(int* __restrict__ cnt,
                                                  const int* __restrict__ bbase) {
    __shared__ int lds[1024];
    const int b = blockIdx.x;
    const int t = threadIdx.x;
    const int i0 = 2 * t, i1 = 2 * t + 1;
    const int a0 = (i0 < SGRD) ? cnt[b * SGRD + i0] : 0;
    const int a1 = (i1 < SGRD) ? cnt[b * SGRD + i1] : 0;
    const int s = a0 + a1;
    lds[t] = s;
    __syncthreads();
    for (int off = 1; off < 1024; off <<= 1) {
        const int y = (t >= off) ? lds[t - off] : 0;
        __syncthreads();
        lds[t] += y;
        __syncthreads();
    }
    const int pre = bbase[b] + lds[t] - s;
    if (i0 < SGRD) cnt[b * SGRD + i0] = pre;
    if (i1 < SGRD) cnt[b * SGRD + i1] = pre + a0;
}

// LDS-staged scatter, records staged in LDS (edges read ONCE, sequentially).
__global__ __launch_bounds__(1024) void k_lscatter(const int* __restrict__ row,
                                                   const int* __restrict__ col,
                                                   const float* __restrict__ val,
                                                   const int* __restrict__ cnt,
                                                   const int* __restrict__ bbase,
                                                   uint2* __restrict__ tmp) {
    __shared__ uint2 stage[SCHUNK];   // 64 KB: full records grouped by bucket
    __shared__ int lstartp[1024];     // local bucket starts, padded w/ sentinel
    __shared__ int gbase[NB];
    __shared__ int cur[NB];
    __shared__ int scratch[1024];

    const int g = blockIdx.x;
    const int t = threadIdx.x;
    const int lo = g * SCHUNK;
    const int hi = (lo + SCHUNK < NNZ_TOTAL) ? lo + SCHUNK : NNZ_TOTAL;
    const int n = hi - lo;

    int lcnt = 0;
    if (t < NB) {
        const int base = cnt[t * SGRD + g];
        gbase[t] = base;
        const int nxt = (g == SGRD - 1) ? bbase[t + 1] : cnt[t * SGRD + g + 1];
        lcnt = nxt - base;
    }
    scratch[t] = lcnt;
    __syncthreads();

    for (int off = 1; off < 1024; off <<= 1) {
        const int y = (t >= off) ? scratch[t - off] : 0;
        __syncthreads();
        scratch[t] += y;
        __syncthreads();
    }
    const int ls = (t < NB) ? scratch[t] - lcnt : n;   // sentinel = n
    lstartp[t] = ls;
    if (t < NB) cur[t] = ls;
    __syncthreads();

    for (int e = lo + t; e < hi; e += 1024) {
        const int r = row[e];
        const unsigned meta = ((unsigned)(r & (BROWS - 1)) << 18) | (unsigned)col[e];
        const int p = atomicAdd(&cur[r >> 8], 1);
        stage[p] = make_uint2(meta, __float_as_uint(val[e]));
    }
    __syncthreads();

    for (int l = t; l < n; l += 1024) {
        int blo = 0, bhi = 1024;
        #pragma unroll
        for (int s = 0; s < 10; ++s) {
            const int mid = (blo + bhi) >> 1;
            if (lstartp[mid] <= l) blo = mid; else bhi = mid;
        }
        tmp[gbase[blo] + (l - lstartp[blo])] = stage[l];
    }
}

// per-bucket counting sort (256 keys = local row), emits PACKED 4-byte CSR
// records (q<<18 | col) and row_offs. Bucket region ~137 KB L2-resident.
__global__ __launch_bounds__(256) void k_bsort(const uint2* __restrict__ tmp,
                                               unsigned* __restrict__ csr,
                                               const int* __restrict__ bbase,
                                               int* __restrict__ row_offs) {
    __shared__ int cnt[BROWS];
    __shared__ int roff[BROWS];
    __shared__ int curl[BROWS];
    const int tid = threadIdx.x;
    const int b = blockIdx.x;
    const int s = bbase[b];
    const int e = bbase[b + 1];

    cnt[tid] = 0;
    __syncthreads();
    for (int j = s + tid; j < e; j += 256)
        atomicAdd(&cnt[tmp[j].x >> 18], 1);
    __syncthreads();
    if (tid == 0) {
        int a = 0;
        #pragma unroll
        for (int k = 0; k < BROWS; ++k) { roff[k] = a; a += cnt[k]; }
    }
    __syncthreads();
    {
        const int gr = b * BROWS + tid;
        if (gr < N_NODES) row_offs[gr] = s + roff[tid];
        curl[tid] = s + roff[tid];
    }
    __syncthreads();
    for (int j = s + tid; j < e; j += 256) {
        const uint2 u = tmp[j];
        const int p = atomicAdd(&curl[u.x >> 18], 1);
        const unsigned q = __float2uint_rn(__uint_as_float(u.y) * VENC);   // 14 bits
        csr[p] = (q << 18) | (u.x & COLMASK);
    }
    if (b == 0 && tid == 0) row_offs[N_NODES] = NNZ_TOTAL;
}

// ===========================================================================
// CSR SpMM, bf16 gather table, 4-byte packed records: one wave per row;
// lane = sub*16 + d4; unroll-4; f32 register accumulate; writes ONLY the
// next-layer bf16 table (no f32 acc traffic).
// ===========================================================================
__global__ __launch_bounds__(256) void k_spmm_bf16(const ushort4* __restrict__ T4,
                                                   ushort4* __restrict__ U4,
                                                   const int* __restrict__ offs,
                                                   const unsigned* __restrict__ csr) {
    const int lane = threadIdx.x & 63;
    const int sub  = lane >> 4;
    const int d4   = lane & 15;
    const int r = blockIdx.x * 4 + (threadIdx.x >> 6);
    const int s = offs[r];
    const int e = offs[r + 1];
    float4 acc = make_float4(0.f, 0.f, 0.f, 0.f);
    int j = s + sub;
    for (; j + 12 < e; j += 16) {
        const unsigned u0 = csr[j];
        const unsigned u1 = csr[j + 4];
        const unsigned u2 = csr[j + 8];
        const unsigned u3 = csr[j + 12];
        const ushort4 g0 = T4[(size_t)(u0 & COLMASK) * 16 + d4];
        const ushort4 g1 = T4[(size_t)(u1 & COLMASK) * 16 + d4];
        const ushort4 g2 = T4[(size_t)(u2 & COLMASK) * 16 + d4];
        const ushort4 g3 = T4[(size_t)(u3 & COLMASK) * 16 + d4];
        const float v0 = (float)(u0 >> 18) * VDEC;
        const float v1 = (float)(u1 >> 18) * VDEC;
        const float v2 = (float)(u2 >> 18) * VDEC;
        const float v3 = (float)(u3 >> 18) * VDEC;
        acc.x += v0 * bf2f(g0.x) + v1 * bf2f(g1.x) + v2 * bf2f(g2.x) + v3 * bf2f(g3.x);
        acc.y += v0 * bf2f(g0.y) + v1 * bf2f(g1.y) + v2 * bf2f(g2.y) + v3 * bf2f(g3.y);
        acc.z += v0 * bf2f(g0.z) + v1 * bf2f(g1.z) + v2 * bf2f(g2.z) + v3 * bf2f(g3.z);
        acc.w += v0 * bf2f(g0.w) + v1 * bf2f(g1.w) + v2 * bf2f(g2.w) + v3 * bf2f(g3.w);
    }
    for (; j + 4 < e; j += 8) {
        const unsigned u0 = csr[j];
        const unsigned u1 = csr[j + 4];
        const ushort4 g0 = T4[(size_t)(u0 & COLMASK) * 16 + d4];
        const ushort4 g1 = T4[(size_t)(u1 & COLMASK) * 16 + d4];
        const float v0 = (float)(u0 >> 18) * VDEC;
        const float v1 = (float)(u1 >> 18) * VDEC;
        acc.x += v0 * bf2f(g0.x) + v1 * bf2f(g1.x);
        acc.y += v0 * bf2f(g0.y) + v1 * bf2f(g1.y);
        acc.z += v0 * bf2f(g0.z) + v1 * bf2f(g1.z);
        acc.w += v0 * bf2f(g0.w) + v1 * bf2f(g1.w);
    }
    if (j < e) {
        const unsigned u0 = csr[j];
        const ushort4 g0 = T4[(size_t)(u0 & COLMASK) * 16 + d4];
        const float v0 = (float)(u0 >> 18) * VDEC;
        acc.x += v0 * bf2f(g0.x);
        acc.y += v0 * bf2f(g0.y);
        acc.z += v0 * bf2f(g0.z);
        acc.w += v0 * bf2f(g0.w);
    }
    #pragma unroll
    for (int m = 16; m <= 32; m <<= 1) {
        acc.x += __shfl_xor(acc.x, m, 64);
        acc.y += __shfl_xor(acc.y, m, 64);
        acc.z += __shfl_xor(acc.z, m, 64);
        acc.w += __shfl_xor(acc.w, m, 64);
    }
    if (sub == 0) {
        const size_t idx = (size_t)r * 16 + d4;
        ushort4 t;
        t.x = f2bf(acc.x); t.y = f2bf(acc.y); t.z = f2bf(acc.z); t.w = f2bf(acc.w);
        U4[idx] = t;
    }
}

// ===========================================================================
// final mean: out = (concat(user,item) + T1 + T2 + T3) * 0.25
// ===========================================================================
__global__ __launch_bounds__(256) void k_mean(const float4* __restrict__ user,
                                              const float4* __restrict__ item,
                                              const ushort4* __restrict__ T1,
                                              const ushort4* __restrict__ T2,
                                              const ushort4* __restrict__ T3,
                                              float4* __restrict__ out) {
    const int stride = gridDim.x * blockDim.x;
    for (int i = blockIdx.x * blockDim.x + threadIdx.x; i < TOTAL4; i += stride) {
        const float4 v = (i < USZ4) ? user[i] : item[i - USZ4];
        const ushort4 a = T1[i];
        const ushort4 b = T2[i];
        const ushort4 c = T3[i];
        float4 o;
        o.x = (v.x + bf2f(a.x) + bf2f(b.x) + bf2f(c.x)) * 0.25f;
        o.y = (v.y + bf2f(a.y) + bf2f(b.y) + bf2f(c.y)) * 0.25f;
        o.z = (v.z + bf2f(a.z) + bf2f(b.z) + bf2f(c.z)) * 0.25f;
        o.w = (v.w + bf2f(a.w) + bf2f(b.w) + bf2f(c.w)) * 0.25f;
        out[i] = o;
    }
}

// ===========================================================================
// Last-resort fallback (round-1 atomic path; needs only 76.8 MB ws)
// ===========================================================================
__global__ __launch_bounds__(256) void k_init_f32(const float4* __restrict__ user,
                                                  const float4* __restrict__ item,
                                                  float4* __restrict__ A,
                                                  float4* __restrict__ acc) {
    const int stride = gridDim.x * blockDim.x;
    for (int i = blockIdx.x * blockDim.x + threadIdx.x; i < TOTAL4; i += stride) {
        float4 v = (i < USZ4) ? user[i] : item[i - USZ4];
        A[i] = v;
        acc[i] = v;
    }
}

__global__ __launch_bounds__(256) void k_spmm_atomic(const float* __restrict__ A,
                                                     float* __restrict__ B,
                                                     const float* __restrict__ val,
                                                     const int* __restrict__ row,
                                                     const int* __restrict__ col) {
    const int lane = threadIdx.x & 63;
    int wave = blockIdx.x * (blockDim.x >> 6) + (threadIdx.x >> 6);
    const int nw = gridDim.x * (blockDim.x >> 6);
    for (int e = wave; e < NNZ_TOTAL; e += nw) {
        const float x = A[col[e] * DIM + lane];
        unsafeAtomicAdd(&B[row[e] * DIM + lane], val[e] * x);
    }
}

__global__ __launch_bounds__(256) void k_accadd(float4* __restrict__ acc,
                                                const float4* __restrict__ B) {
    const int stride = gridDim.x * blockDim.x;
    for (int i = blockIdx.x * blockDim.x + threadIdx.x; i < TOTAL4; i += stride) {
        float4 a = acc[i];
        const float4 b = B[i];
        a.x += b.x; a.y += b.y; a.z += b.z; a.w += b.w;
        acc[i] = a;
    }
}

__global__ __launch_bounds__(256) void k_final(float4* __restrict__ acc,
                                               const float4* __restrict__ B) {
    const int stride = gridDim.x * blockDim.x;
    for (int i = blockIdx.x * blockDim.x + threadIdx.x; i < TOTAL4; i += stride) {
        float4 a = acc[i];
        const float4 b = B[i];
        a.x = (a.x + b.x) * 0.25f;
        a.y = (a.y + b.y) * 0.25f;
        a.z = (a.z + b.z) * 0.25f;
        a.w = (a.w + b.w) * 0.25f;
        acc[i] = a;
    }
}

extern "C" void kernel_launch(void* const* d_in, const int* in_sizes, int n_in,
                              void* d_out, int out_size, void* d_ws, size_t ws_size,
                              hipStream_t stream) {
    const float* user = (const float*)d_in[0];
    const float* item = (const float*)d_in[1];
    const float* val  = (const float*)d_in[2];
    const int*   row  = (const int*)d_in[3];
    const int*   col  = (const int*)d_in[4];

    float* out = (float*)d_out;
    const int eltBlocks = 2048;

    // ws layout: region A [0..40MB): cnt matrix (2.9MB) during build -> csr (packed u32)
    //            region B [40..120MB): tmp (80MB) -> T0|T1|T2|T3 (76.8MB) after bsort
    //            misc: row_offs, bbase, rowsum
    const size_t CSR_BYTES = (size_t)NNZ_TOTAL * 4;            // 40,000,000
    unsigned* csr = (unsigned*)d_ws;
    int*   cnt  = (int*)d_ws;                                   // 2.9MB, dead before bsort writes csr
    char*  reg1 = (char*)d_ws + CSR_BYTES;
    uint2* tmp  = (uint2*)reg1;                                 // 80MB
    ushort4* T0 = (ushort4*)reg1;                               // 19.2MB (overlays tmp after bsort)
    ushort4* T1 = T0 + TOTAL4;
    ushort4* T2 = T1 + TOTAL4;
    ushort4* T3 = T2 + TOTAL4;                                  // ends at 76.8MB < 80MB tmp
    int* row_offs = (int*)(reg1 + (size_t)NNZ_TOTAL * 8);       // N_NODES+1
    int* bbase    = row_offs + N_NODES + 1;                     // NB+1
    int* rowsum   = bbase + NB + 1;                             // NB

    const size_t needed =
        CSR_BYTES + (size_t)NNZ_TOTAL * 8 + (size_t)(N_NODES + 1 + 2 * NB + 2) * 4;

    if (ws_size >= needed) {
        // ---- build bucketed CSR (no global atomics; LDS record staging) ----
        k_lhist<<<SGRD, 256, 0, stream>>>(row, cnt);
        k_rowsum<<<NB, 256, 0, stream>>>(cnt, rowsum);
        k_sscan<<<1, 1024, 0, stream>>>(rowsum, bbase);
        k_rowscan<<<NB, 1024, 0, stream>>>(cnt, bbase);
        k_lscatter<<<SGRD, 1024, 0, stream>>>(row, col, val, cnt, bbase, tmp);
        k_bsort<<<NB, 256, 0, stream>>>(tmp, csr, bbase, row_offs);

        // ---- embeddings (T0..T3 overlay tmp; tmp dead after bsort) ----
        k_init<<<eltBlocks, 256, 0, stream>>>((const float4*)user, (const float4*)item, T0);

        const int rowBlocks = N_NODES / 4;   // 37500
        k_spmm_bf16<<<rowBlocks, 256, 0, stream>>>(T0, T1, row_offs, csr);
        k_spmm_bf16<<<rowBlocks, 256, 0, stream>>>(T1, T2, row_offs, csr);
        k_spmm_bf16<<<rowBlocks, 256, 0, stream>>>(T2, T3, row_offs, csr);

        k_mean<<<eltBlocks, 256, 0, stream>>>((const float4*)user, (const float4*)item,
                                              T1, T2, T3, (float4*)out);
        return;
    }

    // ---- last resort: atomic path ----
    float* A2 = (float*)d_ws;
    float* B2 = A2 + TOTAL;
    k_init_f32<<<eltBlocks, 256, 0, stream>>>((const float4*)user, (const float4*)item,
                                              (float4*)A2, (float4*)out);
    float* Af = A2;
    float* Bf = B2;
    for (int layer = 0; layer < 3; ++layer) {
        hipMemsetAsync(Bf, 0, (size_t)TOTAL * sizeof(float), stream);
        k_spmm_atomic<<<2048, 256, 0, stream>>>(Af, Bf, val, row, col);
        if (layer < 2) {
            k_accadd<<<eltBlocks, 256, 0, stream>>>((float4*)out, (const float4*)Bf);
            float* t = Af; Af = Bf; Bf = t;
        } else {
            k_final<<<eltBlocks, 256, 0, stream>>>((float4*)out, (const float4*)Bf);
        }
    }
}